// Round 9
// baseline (1043.757 us; speedup 1.0000x reference)
//
#include <hip/hip_runtime.h>
#include <hip/hip_bf16.h>

typedef __hip_bfloat16 bft;
typedef __attribute__((ext_vector_type(8))) short bf16x8;
typedef __attribute__((ext_vector_type(4))) float f32x4;

#define BLK 256
static constexpr int Cc = 192;     // channels
static constexpr int L  = 192;     // H = W
static constexpr int S  = 36864;   // L*L
static constexpr int Bn = 2;       // batch
static constexpr int HID = 510;    // int(192*2.66)
static constexpr int PW = 50;      // FFN strip width incl. halo
static constexpr int SW = 48;      // FFN strip output width
static constexpr double PI_D = 3.141592653589793238462643383279502884;

__device__ __forceinline__ float ldf(const float* p) { return *p; }
__device__ __forceinline__ float ldf(const bft* p)   { return __bfloat162float(*p); }
__device__ __forceinline__ void  stf(float* p, float v) { *p = v; }
__device__ __forceinline__ void  stf(bft* p, float v)   { *p = __float2bfloat16(v); }
__device__ __forceinline__ unsigned short f2bfu(float f) {
    bft h = __float2bfloat16(f);
    return *reinterpret_cast<const unsigned short*>(&h);
}
__device__ __forceinline__ unsigned short bfu(const bft* p) {
    return *reinterpret_cast<const unsigned short*>(p);
}
__device__ __forceinline__ float bu2f(unsigned short u) {
    unsigned int x = (unsigned int)u << 16;
    return __uint_as_float(x);
}
__device__ __forceinline__ bf16x8 ld8(const unsigned short* p) {   // 4B-aligned
    union { unsigned int u[4]; bf16x8 v; } t;
    const unsigned int* q = reinterpret_cast<const unsigned int*>(p);
    t.u[0] = q[0]; t.u[1] = q[1]; t.u[2] = q[2]; t.u[3] = q[3];
    return t.v;
}

// ---------------- DCT matrix init -> bf16 direct + transposed ----------------
__global__ __launch_bounds__(BLK) void k_dct_init(bft* __restrict__ dctb,
                                                  bft* __restrict__ dctTb) {
    int idx = blockIdx.x * BLK + threadIdx.x;
    if (idx >= L * L) return;
    int p = idx / L, h = idx - p * L;
    double v = (p == 0) ? sqrt(1.0 / L)
                        : cos(PI_D * p * (2 * h + 1) / (2.0 * L)) * sqrt(2.0 / L);
    bft bv = __float2bfloat16((float)v);
    dctb[p * L + h] = bv;
    dctTb[h * L + p] = bv;
}

// ---------------- fp32 weight -> bf16 with zero pad --------------------------
__global__ __launch_bounds__(BLK) void k_cvt(const float* __restrict__ src,
                                             bft* __restrict__ dst,
                                             int Mr, int Kr, int Kp) {
    int idx = blockIdx.x * BLK + threadIdx.x;   // [0, Mp*Kp)
    int m = idx / Kp, k = idx - m * Kp;
    float v = (m < Mr && k < Kr) ? src[(size_t)m * Kr + k] : 0.f;
    dst[idx] = __float2bfloat16(v);
}

// ---------------- LayerNorm over channel dim: NCHW out -----------------------
template <typename TI>
__global__ __launch_bounds__(BLK) void k_ln(const TI* __restrict__ x,
                                            const float* __restrict__ w,
                                            const float* __restrict__ b,
                                            bft* __restrict__ out) {
    int s = blockIdx.x * BLK + threadIdx.x;   // [0, S)
    const TI* xp = x + s;
    float sum = 0.f, sq = 0.f;
    for (int c = 0; c < Cc; ++c) {
        float v = ldf(xp + (size_t)c * S);
        sum += v; sq += v * v;
    }
    float mu = sum * (1.f / Cc);
    float var = sq * (1.f / Cc) - mu * mu;
    float r = rsqrtf(var + 1e-5f);
    for (int c = 0; c < Cc; ++c) {
        float v = ldf(xp + (size_t)c * S);
        stf(out + s + (size_t)c * S, (v - mu) * r * w[c] + b[c]);
    }
}

// ---------------- LayerNorm: transposed out z^T [s][c] -----------------------
template <typename TI>
__global__ __launch_bounds__(BLK) void k_lnT(const TI* __restrict__ x,
                                             const float* __restrict__ w,
                                             const float* __restrict__ b,
                                             bft* __restrict__ out) {
    int s = blockIdx.x * BLK + threadIdx.x;
    const TI* xp = x + s;
    float sum = 0.f, sq = 0.f;
    for (int c = 0; c < Cc; ++c) {
        float v = ldf(xp + (size_t)c * S);
        sum += v; sq += v * v;
    }
    float mu = sum * (1.f / Cc);
    float var = sq * (1.f / Cc) - mu * mu;
    float r = rsqrtf(var + 1e-5f);
    bft* op = out + (size_t)s * Cc;
    for (int c0 = 0; c0 < Cc; c0 += 8) {
        unsigned short v8[8];
#pragma unroll
        for (int q = 0; q < 8; ++q) {
            float v = ldf(xp + (size_t)(c0 + q) * S);
            v8[q] = f2bfu((v - mu) * r * w[c0 + q] + b[c0 + q]);
        }
        *reinterpret_cast<uint4*>(op + c0) = *reinterpret_cast<uint4*>(v8);
    }
}

// ---------------- transpose [Cc][S] -> [S][Cc] -------------------------------
__global__ __launch_bounds__(BLK) void k_tr(const bft* __restrict__ in,
                                            bft* __restrict__ out) {
    __shared__ unsigned short t[32][72];
    const int tid = threadIdx.x;
    const int s0 = blockIdx.x * 64, c0 = blockIdx.y * 32;
    {   // load 32c x 64s
        int c = tid >> 3, sc = (tid & 7) * 8;
        *reinterpret_cast<uint4*>(&t[c][sc]) =
            *reinterpret_cast<const uint4*>(in + (size_t)(c0 + c) * S + s0 + sc);
    }
    __syncthreads();
    {   // write 64s x 32c
        int s = tid >> 2, cc = (tid & 3) * 8;
        unsigned short v[8];
#pragma unroll
        for (int q = 0; q < 8; ++q) v[q] = t[cc + q][s];
        *reinterpret_cast<uint4*>(out + (size_t)(s0 + s) * Cc + c0 + cc) =
            *reinterpret_cast<uint4*>(v);
    }
}

// =============================================================================
// Unified MFMA bf16 GEMM. Block = (WR*FM*16) x (WC*FN*16), 4 waves (WR x WC),
// BK=32.
//   BMODE: 0 = legacy col-major [k][n] scalar stage; 2 = row-major [n][k]
//          vector stage; 3 = row-major strip: row = map(n) into z^T [S][Cc]
//   OMODE: 0 = linear; 1 = FFN strip scatter; 2 = window-tiled -> spatial;
//          3 = transposed packed: idx = n*strideO + m, 8B stores
// =============================================================================
template <int WR, int WC, int FM, int FN, int BMODE, int OMODE,
          bool HASBIAS, bool HASRES, typename OutT, typename ResT>
__global__ __launch_bounds__(256) void k_mm(
    const bft* __restrict__ A, int strideA, int Mreal, long zA,
    const bft* __restrict__ B, int strideB, long zB,
    OutT* __restrict__ Out, int strideO, long zO,
    const float* __restrict__ bias,
    const ResT* __restrict__ Res, long zR,
    int K, int w0) {
    constexpr int BM = WR * FM * 16, BN = WC * FN * 16;
    __shared__ unsigned short Al[BM][40];
    __shared__ unsigned short Bl[BN][40];
    const int tid = threadIdx.x;
    const int n0 = blockIdx.x * BN, m0 = blockIdx.y * BM, bz = blockIdx.z;
    const int lane = tid & 63, wv = tid >> 6;
    const int wr = wv / WC, wc = wv % WC;
    const int l15 = lane & 15, l4 = lane >> 4;
    f32x4 acc[FM][FN] = {};

    constexpr int AE = BM / 8;
    constexpr int TPR = 256 / BM;
    const int arow = tid / TPR, akc = (tid % TPR) * AE;
    // legacy col staging vars
    int bn = 0, bk = 0;
    if constexpr (BMODE == 0) { bn = tid & 127; bk = (tid >> 7) * 16; }

    const bft* Ab = A + (size_t)bz * zA;
    const bft* Bb = B + (size_t)bz * zB;
    int gm = m0 + arow; if (gm >= Mreal) gm = Mreal - 1;

    for (int k0 = 0; k0 < K; k0 += 32) {
        {   // stage A (row-major, vectorized)
            const bft* src = Ab + (size_t)gm * strideA + k0 + akc;
#pragma unroll
            for (int q = 0; q < AE / 8; ++q)
                *reinterpret_cast<uint4*>(&Al[arow][akc + 8 * q]) =
                    *reinterpret_cast<const uint4*>(src + 8 * q);
        }
        if constexpr (BMODE == 0) {   // legacy: scalar col gather
            unsigned short v[16];
            const bft* src = Bb + (size_t)(k0 + bk) * strideB + n0 + bn;
#pragma unroll
            for (int e = 0; e < 16; ++e) v[e] = bfu(src + (size_t)e * strideB);
#pragma unroll
            for (int q = 0; q < 2; ++q)
                *reinterpret_cast<uint4*>(&Bl[bn][bk + 8 * q]) =
                    *reinterpret_cast<uint4*>(&v[8 * q]);
        } else {                      // row-major vector staging
            for (int id = tid; id < BN * 4; id += 256) {
                int row = id >> 2, kc = (id & 3) * 8;
                uint4 val;
                if constexpr (BMODE == 2) {
                    val = *reinterpret_cast<const uint4*>(
                        Bb + (size_t)(n0 + row) * strideB + k0 + kc);
                } else {  // BMODE 3: strip row map into z^T [S][Cc]
                    int gn = n0 + row;
                    int h = gn / PW, wl = gn - h * PW;
                    int wg = w0 - 1 + wl;
                    if (wg >= 0 && wg < L)
                        val = *reinterpret_cast<const uint4*>(
                            Bb + (size_t)(h * L + wg) * Cc + k0 + kc);
                    else
                        val = make_uint4(0, 0, 0, 0);
                }
                *reinterpret_cast<uint4*>(&Bl[row][kc]) = val;
            }
        }
        __syncthreads();
        bf16x8 af[FM], bf[FN];
#pragma unroll
        for (int i = 0; i < FM; ++i)
            af[i] = *reinterpret_cast<const bf16x8*>(
                &Al[wr * FM * 16 + i * 16 + l15][l4 * 8]);
#pragma unroll
        for (int j = 0; j < FN; ++j)
            bf[j] = *reinterpret_cast<const bf16x8*>(
                &Bl[wc * FN * 16 + j * 16 + l15][l4 * 8]);
#pragma unroll
        for (int i = 0; i < FM; ++i)
#pragma unroll
            for (int j = 0; j < FN; ++j)
                acc[i][j] = __builtin_amdgcn_mfma_f32_16x16x32_bf16(
                    af[i], bf[j], acc[i][j], 0, 0, 0);
        __syncthreads();
    }
    if constexpr (OMODE == 3) {       // transposed packed write: n*strideO + m
#pragma unroll
        for (int i = 0; i < FM; ++i) {
            int mB = m0 + wr * FM * 16 + i * 16 + l4 * 4;
#pragma unroll
            for (int j = 0; j < FN; ++j) {
                int n = n0 + wc * FN * 16 + j * 16 + l15;
                unsigned short v[4];
#pragma unroll
                for (int r = 0; r < 4; ++r) v[r] = f2bfu(acc[i][j][r]);
                *reinterpret_cast<uint2*>((bft*)Out + (size_t)bz * zO
                    + (size_t)n * strideO + mB) = *reinterpret_cast<uint2*>(v);
            }
        }
        return;
    }
#pragma unroll
    for (int i = 0; i < FM; ++i) {
        int mB = m0 + wr * FM * 16 + i * 16 + l4 * 4;
#pragma unroll
        for (int j = 0; j < FN; ++j) {
            int n = n0 + wc * FN * 16 + j * 16 + l15;
#pragma unroll
            for (int r = 0; r < 4; ++r) {
                int m = mB + r;
                if (m >= Mreal) continue;
                float vv = acc[i][j][r];
                if constexpr (HASBIAS) vv += bias[m];
                size_t idx;
                if constexpr (OMODE == 0)
                    idx = (size_t)bz * zO + (size_t)m * strideO + n;
                else if constexpr (OMODE == 1) {
                    int h = n / SW, wl = n - h * SW;
                    idx = (size_t)m * S + (size_t)h * L + w0 + wl;
                } else {
                    int win = n >> 6, e = n & 63;
                    int hh = ((win / 24) << 3) + (e >> 3);
                    int ww = ((win % 24) << 3) + (e & 7);
                    idx = (size_t)m * S + (size_t)hh * L + ww;
                }
                if constexpr (HASRES) vv += ldf(Res + ((OMODE == 0)
                                  ? ((size_t)bz * zR + (size_t)m * strideO + n) : idx));
                stf(Out + idx, vv);
            }
        }
    }
}

// ---------------- depthwise 3x3 (8 outputs/thread) -> window-tiled -----------
__global__ __launch_bounds__(BLK) void k_dwconv(const bft* __restrict__ in,
                                                const float* __restrict__ wt,
                                                bft* __restrict__ out) {
    int t = blockIdx.x * BLK + threadIdx.x;      // [0, Cc*S/8)
    int ch = t / (S / 8);
    int rem = t - ch * (S / 8);
    int h = rem / 24, wb = (rem - h * 24) * 8;
    const float* wp = wt + (size_t)ch * 9;
    const bft* ip = in + (size_t)ch * S;
    float acc[8] = {};
#pragma unroll
    for (int dy = -1; dy <= 1; ++dy) {
        int hh = h + dy;
        if (hh < 0 || hh >= L) continue;
        const bft* rp = ip + hh * L + wb;
        float e[10];
        uint4 mid = *reinterpret_cast<const uint4*>(rp);
        const unsigned short* ms = reinterpret_cast<const unsigned short*>(&mid);
#pragma unroll
        for (int q = 0; q < 8; ++q) e[q + 1] = bu2f(ms[q]);
        e[0] = (wb > 0) ? ldf(rp - 1) : 0.f;
        e[9] = (wb + 8 < L) ? ldf(rp + 8) : 0.f;
        float c0 = wp[(dy + 1) * 3], c1 = wp[(dy + 1) * 3 + 1], c2 = wp[(dy + 1) * 3 + 2];
#pragma unroll
        for (int q = 0; q < 8; ++q)
            acc[q] += c0 * e[q] + c1 * e[q + 1] + c2 * e[q + 2];
    }
    int win = (h >> 3) * 24 + (wb >> 3);
    int e0 = (h & 7) * 8;
    unsigned short ov[8];
#pragma unroll
    for (int q = 0; q < 8; ++q) ov[q] = f2bfu(acc[q]);
    *reinterpret_cast<uint4*>(out + (size_t)ch * S + win * 64 + e0) =
        *reinterpret_cast<uint4*>(ov);
}

// ---------------- window channel attention via MFMA; out = [s*][Cc] ----------
__global__ __launch_bounds__(256) void k_attn_mfma(const bft* __restrict__ QW,
                                                   const bft* __restrict__ KW,
                                                   const bft* __restrict__ VW,
                                                   const float* __restrict__ temp,
                                                   bft* __restrict__ outp) {
    __shared__ unsigned short qls[4][32 * 66];
    __shared__ unsigned short kls[4][32 * 66];
    __shared__ unsigned short vls[4][32 * 66];
    __shared__ float rqs[4][32], rks[4][32];
    const int tid = threadIdx.x;
    const int wv = tid >> 6, lane = tid & 63;
    const int win = blockIdx.x * 4 + wv;
    const int hd = blockIdx.y;
    const int l15 = lane & 15, l4 = lane >> 4;
    unsigned short* ql = qls[wv];
    unsigned short* kl = kls[wv];
    unsigned short* vl = vls[wv];
    const size_t base = (size_t)(hd * 32) * S + (size_t)win * 64;

#pragma unroll
    for (int i = 0; i < 4; ++i) {
        int c = i * 8 + (lane >> 3), e0 = (lane & 7) * 8;
        size_t g = base + (size_t)c * S + e0;
        uint4 vq = *reinterpret_cast<const uint4*>(QW + g);
        uint4 vk = *reinterpret_cast<const uint4*>(KW + g);
        uint4 vvv = *reinterpret_cast<const uint4*>(VW + g);
        unsigned int* dq = reinterpret_cast<unsigned int*>(&ql[c * 66 + e0]);
        unsigned int* dk = reinterpret_cast<unsigned int*>(&kl[c * 66 + e0]);
        unsigned int* dv = reinterpret_cast<unsigned int*>(&vl[c * 66 + e0]);
        dq[0] = vq.x; dq[1] = vq.y; dq[2] = vq.z; dq[3] = vq.w;
        dk[0] = vk.x; dk[1] = vk.y; dk[2] = vk.z; dk[3] = vk.w;
        dv[0] = vvv.x; dv[1] = vvv.y; dv[2] = vvv.z; dv[3] = vvv.w;
    }
    __syncthreads();
    {
        int row = lane & 31;
        const unsigned short* src = (lane < 32) ? ql : kl;
        float s = 0.f;
#pragma unroll
        for (int w = 0; w < 32; ++w) {
            unsigned int d = *reinterpret_cast<const unsigned int*>(&src[row * 66 + 2 * w]);
            float a = bu2f((unsigned short)(d & 0xffff));
            float b = bu2f((unsigned short)(d >> 16));
            s += a * a + b * b;
        }
        float r = 1.f / fmaxf(sqrtf(s), 1e-12f);
        if (lane < 32) rqs[wv][row] = r; else rks[wv][row] = r;
    }
    __syncthreads();
    f32x4 at[2][2] = {};
#pragma unroll
    for (int ks = 0; ks < 2; ++ks) {
        bf16x8 aq[2], bk[2];
#pragma unroll
        for (int i = 0; i < 2; ++i)
            aq[i] = ld8(&ql[(i * 16 + l15) * 66 + ks * 32 + l4 * 8]);
#pragma unroll
        for (int j = 0; j < 2; ++j)
            bk[j] = ld8(&kl[(j * 16 + l15) * 66 + ks * 32 + l4 * 8]);
#pragma unroll
        for (int i = 0; i < 2; ++i)
#pragma unroll
            for (int j = 0; j < 2; ++j)
                at[i][j] = __builtin_amdgcn_mfma_f32_16x16x32_bf16(
                    aq[i], bk[j], at[i][j], 0, 0, 0);
    }
    float tpr = temp[hd];
    float rk0 = rks[wv][l15] * tpr, rk1 = rks[wv][16 + l15] * tpr;
    float pr[2][2][4];
#pragma unroll
    for (int i = 0; i < 2; ++i)
#pragma unroll
        for (int r = 0; r < 4; ++r) {
            int c = i * 16 + l4 * 4 + r;
            float rq = rqs[wv][c];
            float v0 = at[i][0][r] * rq * rk0;
            float v1 = at[i][1][r] * rq * rk1;
            float mx = fmaxf(v0, v1);
#pragma unroll
            for (int m = 1; m < 16; m <<= 1) mx = fmaxf(mx, __shfl_xor(mx, m));
            v0 = __expf(v0 - mx);
            v1 = __expf(v1 - mx);
            float sm = v0 + v1;
#pragma unroll
            for (int m = 1; m < 16; m <<= 1) sm += __shfl_xor(sm, m);
            float inv = 1.f / sm;
            pr[i][0][r] = v0 * inv;
            pr[i][1][r] = v1 * inv;
        }
    __syncthreads();
    unsigned short* pl = ql;
#pragma unroll
    for (int i = 0; i < 2; ++i)
#pragma unroll
        for (int j = 0; j < 2; ++j)
#pragma unroll
            for (int r = 0; r < 4; ++r)
                pl[(i * 16 + l4 * 4 + r) * 34 + j * 16 + l15] = f2bfu(pr[i][j][r]);
    __syncthreads();
    bf16x8 ap[2];
#pragma unroll
    for (int i = 0; i < 2; ++i)
        ap[i] = ld8(&pl[(i * 16 + l15) * 34 + l4 * 8]);
    f32x4 o[2][4] = {};
#pragma unroll
    for (int j = 0; j < 4; ++j) {
        unsigned short tv[8];
#pragma unroll
        for (int q = 0; q < 8; ++q)
            tv[q] = vl[(l4 * 8 + q) * 66 + j * 16 + l15];
        bf16x8 bv = *reinterpret_cast<bf16x8*>(tv);
#pragma unroll
        for (int i = 0; i < 2; ++i)
            o[i][j] = __builtin_amdgcn_mfma_f32_16x16x32_bf16(ap[i], bv, o[i][j], 0, 0, 0);
    }
    // write attnT [s* = win*64+e][c], packed 4-c chunks (8B)
#pragma unroll
    for (int i = 0; i < 2; ++i) {
        int c0 = hd * 32 + i * 16 + l4 * 4;
#pragma unroll
        for (int j = 0; j < 4; ++j) {
            int e = j * 16 + l15;
            unsigned short v[4];
#pragma unroll
            for (int r = 0; r < 4; ++r) v[r] = f2bfu(o[i][j][r]);
            *reinterpret_cast<uint2*>(outp + (size_t)(win * 64 + e) * Cc + c0) =
                *reinterpret_cast<uint2*>(v);
        }
    }
}

// ---------------- FFN gate on strip (vectorized, 8 outputs/thread) -----------
__global__ __launch_bounds__(BLK) void k_gate(const bft* __restrict__ f,
                                              const float* __restrict__ wt,
                                              bft* __restrict__ g) {
    const int NS = L * PW, NG = L * SW;  // 9600, 9216
    int t = blockIdx.x * BLK + threadIdx.x;       // HID * L * 6
    int c = t / (L * 6);
    int rr = t - c * (L * 6);
    int h = rr / 6, wl0 = (rr - h * 6) * 8;
    const bft* f1 = f + (size_t)c * NS;
    const bft* f2 = f + (size_t)(c + HID) * NS;
    float w1[9], w2[9];
#pragma unroll
    for (int i = 0; i < 9; ++i) {
        w1[i] = wt[(size_t)c * 9 + i];
        w2[i] = wt[((size_t)c + HID) * 9 + i];
    }
    float a1[8], a2[8];
#pragma unroll
    for (int j = 0; j < 8; ++j) { a1[j] = 0.f; a2[j] = 0.f; }
#pragma unroll
    for (int dy = 0; dy < 3; ++dy) {
        int hh = h + dy - 1;
        if (hh < 0 || hh >= L) continue;
        float e1[10], e2[10];
        const unsigned int* p1 =
            reinterpret_cast<const unsigned int*>(f1 + (size_t)hh * PW + wl0);
        const unsigned int* p2 =
            reinterpret_cast<const unsigned int*>(f2 + (size_t)hh * PW + wl0);
#pragma unroll
        for (int q = 0; q < 5; ++q) {
            unsigned int d1 = p1[q], d2 = p2[q];
            e1[2 * q]     = bu2f((unsigned short)(d1 & 0xffff));
            e1[2 * q + 1] = bu2f((unsigned short)(d1 >> 16));
            e2[2 * q]     = bu2f((unsigned short)(d2 & 0xffff));
            e2[2 * q + 1] = bu2f((unsigned short)(d2 >> 16));
        }
#pragma unroll
        for (int dx = 0; dx < 3; ++dx) {
            float ww1 = w1[dy * 3 + dx], ww2 = w2[dy * 3 + dx];
#pragma unroll
            for (int j = 0; j < 8; ++j) {
                a1[j] += ww1 * e1[j + dx];
                a2[j] += ww2 * e2[j + dx];
            }
        }
    }
    unsigned short ov[8];
#pragma unroll
    for (int j = 0; j < 8; ++j) {
        float ge = 0.5f * a1[j] * (1.f + erff(a1[j] * 0.70710678118654752f));
        ov[j] = f2bfu(ge * a2[j]);
    }
    *reinterpret_cast<uint4*>(g + (size_t)c * NG + (size_t)h * SW + wl0) =
        *reinterpret_cast<uint4*>(ov);
}

// -----------------------------------------------------------------------------
extern "C" void kernel_launch(void* const* d_in, const int* in_sizes, int n_in,
                              void* d_out, int out_size, void* d_ws, size_t ws_size,
                              hipStream_t stream) {
    const float* x      = (const float*)d_in[0];
    const float* n1w    = (const float*)d_in[1];
    const float* n1b    = (const float*)d_in[2];
    const float* w_qkv  = (const float*)d_in[3];
    const float* w_dw   = (const float*)d_in[4];
    const float* temp   = (const float*)d_in[5];
    const float* w_proj = (const float*)d_in[6];
    const float* b_proj = (const float*)d_in[7];
    const float* n2w    = (const float*)d_in[8];
    const float* n2b    = (const float*)d_in[9];
    const float* w_in   = (const float*)d_in[10];
    const float* w_dwf  = (const float*)d_in[11];
    const float* w_out  = (const float*)d_in[12];
    float* outp = (float*)d_out;

    // workspace layout: 100,122,624 bytes (unchanged)
    const size_t DCT_B = 147456;
    const size_t CS    = (size_t)Cc * S;
    const size_t X1_B  = (size_t)Bn * CS * 2;
    const size_t P_B   = CS * 2;
    const size_t WB_B  = 884736;
    const size_t NEED  = DCT_B + X1_B + 2 * P_B + (size_t)3 * CS * 2 + WB_B;
    if (ws_size < NEED) return;

    char* p = (char*)d_ws;
    bft* dctb  = (bft*)p;                  // [192][192] = Mh = Mw
    bft* dctTb = dctb + L * L;             // transposed
    p += DCT_B;
    bft* X1    = (bft*)p;                  p += X1_B;
    bft* Pb    = (bft*)p;                  p += P_B;
    bft* Qb    = (bft*)p;                  p += P_B;
    bft* QKV   = (bft*)p;                  p += 3 * CS * 2;
    bft* w_qkv_b = (bft*)p;
    bft* w_proj_b = w_qkv_b + 576 * 192;
    bft* w_in_b  = w_proj_b + 192 * 192;   // 1024x192 (pad M)
    bft* w_out_b = w_in_b + 1024 * 192;    // 192x512 (pad K)
    bft* fbuf  = QKV;                      // [1024][9600]
    bft* gstrip = Qb;                      // [512][9216]
    bft* attnT = QKV + CS;                 // [36864][192]

    k_dct_init<<<144, BLK, 0, stream>>>(dctb, dctTb);
    k_cvt<<<432, BLK, 0, stream>>>(w_qkv, w_qkv_b, 576, 192, 192);
    k_cvt<<<144, BLK, 0, stream>>>(w_proj, w_proj_b, 192, 192, 192);
    k_cvt<<<768, BLK, 0, stream>>>(w_in, w_in_b, 1020, 192, 192);
    k_cvt<<<384, BLK, 0, stream>>>(w_out, w_out_b, 192, 510, 512);

    for (int b = 0; b < Bn; ++b) {
        const float* xb = x + (size_t)b * CS;
        bft* x1b = X1 + (size_t)b * CS;
        // LN1 -> z1 NCHW (Pb)
        k_ln<float><<<S / BLK, BLK, 0, stream>>>(xb, n1w, n1b, Pb);
        // G1 (per c): D[h][p] = z1_c . dctb^T -> Tt[p][h] (Qb, OMODE3)
        k_mm<2, 2, 2, 6, 2, 3, false, false, bft, float><<<dim3(1, 3, Cc), 256, 0, stream>>>(
            Pb, L, L, S,  dctb, L, 0,  Qb, L, S,  nullptr, nullptr, 0,  L, 0);
        // G2 (per c): D[p][q] = Tt_c . dctb^T -> yd[c][q*192+p] (Pb, OMODE3)
        k_mm<2, 2, 2, 6, 2, 3, false, false, bft, float><<<dim3(1, 3, Cc), 256, 0, stream>>>(
            Qb, L, L, S,  dctb, L, 0,  Pb, L, S,  nullptr, nullptr, 0,  L, 0);
        // transpose yd -> ydT [s'][c] (Qb)
        k_tr<<<dim3(576, 6), BLK, 0, stream>>>(Pb, Qb);
        // qkv = W_qkv . ydT^T -> QKV [576][S]
        k_mm<2, 2, 4, 4, 2, 0, false, false, bft, float><<<dim3(288, 5, 1), 256, 0, stream>>>(
            w_qkv_b, Cc, 576, 0,  Qb, Cc, 0,  QKV, S, 0,  nullptr, nullptr, 0,  Cc, 0);
        // depthwise 3x3 -> window-tiled: q->Pb, k->Qb, v->QKV[0:CS]
        k_dwconv<<<(Cc * S / 8) / BLK, BLK, 0, stream>>>(QKV, w_dw, Pb);
        k_dwconv<<<(Cc * S / 8) / BLK, BLK, 0, stream>>>(QKV + CS, w_dw + Cc * 9, Qb);
        k_dwconv<<<(Cc * S / 8) / BLK, BLK, 0, stream>>>(QKV + 2 * CS, w_dw + 2 * Cc * 9, QKV);
        // attention -> attnT [s*][c] (QKV+CS)
        k_attn_mfma<<<dim3(144, 6), 256, 0, stream>>>(Pb, Qb, QKV, temp, attnT);
        // proj + bias; B=attnT rows; window-decode epilogue -> Pb NCHW
        k_mm<2, 2, 4, 4, 2, 2, true, false, bft, float><<<dim3(288, 2, 1), 256, 0, stream>>>(
            w_proj_b, Cc, Cc, 0,  attnT, Cc, 0,  Pb, S, 0,  b_proj, nullptr, 0,  Cc, 0);
        // G3 (per c): D[q][w'] = P_c . dctTb^T -> Ut[w'][q] (Qb, OMODE3)
        k_mm<2, 2, 2, 6, 2, 3, false, false, bft, float><<<dim3(1, 3, Cc), 256, 0, stream>>>(
            Pb, L, L, S,  dctTb, L, 0,  Qb, L, S,  nullptr, nullptr, 0,  L, 0);
        // G4 (per c): D[h'][w'] = dctTb . Ut^T + x -> x1 NCHW
        k_mm<2, 2, 2, 6, 2, 0, false, true, bft, float><<<dim3(1, 3, Cc), 256, 0, stream>>>(
            dctTb, L, L, 0,  Qb, L, S,  x1b, L, S,  nullptr, xb, S,  L, 0);
    }
    for (int b = 0; b < Bn; ++b) {
        bft* x1b = X1 + (size_t)b * CS;
        float* outb = outp + (size_t)b * CS;
        // LN2 -> z^T [s][c] (Pb)
        k_lnT<bft><<<S / BLK, BLK, 0, stream>>>(x1b, n2w, n2b, Pb);
        for (int st = 0; st < 4; ++st) {
            int w0 = st * SW;
            // f = W_in . z (strip rows of z^T) -> fbuf [1024][9600]
            k_mm<2, 2, 4, 4, 3, 0, false, false, bft, float><<<dim3(75, 8, 1), 256, 0, stream>>>(
                w_in_b, Cc, 1024, 0,  Pb, Cc, 0,  fbuf, L * PW, 0,
                nullptr, nullptr, 0,  Cc, w0);
            // gated dwconv + GELU
            k_gate<<<(HID * L * 6) / BLK, BLK, 0, stream>>>(fbuf, w_dwf, gstrip);
            // out = W_out . g + x1 (legacy col-stage B, strip scatter)
            k_mm<2, 2, 4, 4, 0, 1, false, true, float, bft><<<dim3(72, 2, 1), 256, 0, stream>>>(
                w_out_b, 512, Cc, 0,  gstrip, L * SW, 0,  outb, 0, 0,
                nullptr, x1b, 0,  512, w0);
        }
    }
}

// Round 10
// 1023.722 us; speedup vs baseline: 1.0196x; 1.0196x over previous
//
#include <hip/hip_runtime.h>
#include <hip/hip_bf16.h>

typedef __hip_bfloat16 bft;
typedef __attribute__((ext_vector_type(8))) short bf16x8;
typedef __attribute__((ext_vector_type(4))) float f32x4;

#define BLK 256
static constexpr int Cc = 192;     // channels
static constexpr int L  = 192;     // H = W
static constexpr int S  = 36864;   // L*L
static constexpr int Bn = 2;       // batch
static constexpr int HID = 510;    // int(192*2.66)
static constexpr int PW = 50;      // FFN strip width incl. halo
static constexpr int SW = 48;      // FFN strip output width
static constexpr double PI_D = 3.141592653589793238462643383279502884;

__device__ __forceinline__ float ldf(const float* p) { return *p; }
__device__ __forceinline__ float ldf(const bft* p)   { return __bfloat162float(*p); }
__device__ __forceinline__ void  stf(float* p, float v) { *p = v; }
__device__ __forceinline__ void  stf(bft* p, float v)   { *p = __float2bfloat16(v); }
__device__ __forceinline__ unsigned short f2bfu(float f) {
    bft h = __float2bfloat16(f);
    return *reinterpret_cast<const unsigned short*>(&h);
}
__device__ __forceinline__ unsigned short bfu(const bft* p) {
    return *reinterpret_cast<const unsigned short*>(p);
}
__device__ __forceinline__ float bu2f(unsigned short u) {
    unsigned int x = (unsigned int)u << 16;
    return __uint_as_float(x);
}
__device__ __forceinline__ bf16x8 ld8(const unsigned short* p) {   // 4B-aligned
    union { unsigned int u[4]; bf16x8 v; } t;
    const unsigned int* q = reinterpret_cast<const unsigned int*>(p);
    t.u[0] = q[0]; t.u[1] = q[1]; t.u[2] = q[2]; t.u[3] = q[3];
    return t.v;
}

// ---------------- DCT matrix init -> bf16 direct + transposed ----------------
__global__ __launch_bounds__(BLK) void k_dct_init(bft* __restrict__ dctb,
                                                  bft* __restrict__ dctTb) {
    int idx = blockIdx.x * BLK + threadIdx.x;
    if (idx >= L * L) return;
    int p = idx / L, h = idx - p * L;
    double v = (p == 0) ? sqrt(1.0 / L)
                        : cos(PI_D * p * (2 * h + 1) / (2.0 * L)) * sqrt(2.0 / L);
    bft bv = __float2bfloat16((float)v);
    dctb[p * L + h] = bv;
    dctTb[h * L + p] = bv;
}

// ---------------- fp32 weight -> bf16 with zero pad --------------------------
__global__ __launch_bounds__(BLK) void k_cvt(const float* __restrict__ src,
                                             bft* __restrict__ dst,
                                             int Mr, int Kr, int Kp) {
    int idx = blockIdx.x * BLK + threadIdx.x;   // [0, Mp*Kp)
    int m = idx / Kp, k = idx - m * Kp;
    float v = (m < Mr && k < Kr) ? src[(size_t)m * Kr + k] : 0.f;
    dst[idx] = __float2bfloat16(v);
}

// ---------------- LayerNorm, 8 lanes/pixel, NCHW out -------------------------
template <typename TI>
__global__ __launch_bounds__(BLK) void k_ln8(const TI* __restrict__ x,
                                             const float* __restrict__ w,
                                             const float* __restrict__ b,
                                             bft* __restrict__ out) {
    int t = blockIdx.x * BLK + threadIdx.x;   // [0, S*8)
    int s = t >> 3, u = t & 7;                // pixel, channel-group
    const TI* xp = x + s;
    float sum = 0.f, sq = 0.f;
#pragma unroll
    for (int j = 0; j < 24; ++j) {
        float v = ldf(xp + (size_t)(u * 24 + j) * S);
        sum += v; sq += v * v;
    }
#pragma unroll
    for (int m = 1; m < 8; m <<= 1) {
        sum += __shfl_xor(sum, m);
        sq  += __shfl_xor(sq, m);
    }
    float mu = sum * (1.f / Cc);
    float var = sq * (1.f / Cc) - mu * mu;
    float r = rsqrtf(var + 1e-5f);
#pragma unroll
    for (int j = 0; j < 24; ++j) {
        int c = u * 24 + j;
        float v = ldf(xp + (size_t)c * S);
        stf(out + (size_t)c * S + s, (v - mu) * r * w[c] + b[c]);
    }
}

// ---------------- LayerNorm, 8 lanes/pixel, transposed out z^T [s][c] --------
template <typename TI>
__global__ __launch_bounds__(BLK) void k_lnT8(const TI* __restrict__ x,
                                              const float* __restrict__ w,
                                              const float* __restrict__ b,
                                              bft* __restrict__ out) {
    int t = blockIdx.x * BLK + threadIdx.x;
    int s = t >> 3, u = t & 7;
    const TI* xp = x + s;
    float sum = 0.f, sq = 0.f;
#pragma unroll
    for (int j = 0; j < 24; ++j) {
        float v = ldf(xp + (size_t)(u * 24 + j) * S);
        sum += v; sq += v * v;
    }
#pragma unroll
    for (int m = 1; m < 8; m <<= 1) {
        sum += __shfl_xor(sum, m);
        sq  += __shfl_xor(sq, m);
    }
    float mu = sum * (1.f / Cc);
    float var = sq * (1.f / Cc) - mu * mu;
    float r = rsqrtf(var + 1e-5f);
    bft* op = out + (size_t)s * Cc + u * 24;
#pragma unroll
    for (int q = 0; q < 3; ++q) {
        unsigned short v8[8];
#pragma unroll
        for (int jj = 0; jj < 8; ++jj) {
            int c = u * 24 + q * 8 + jj;
            float v = ldf(xp + (size_t)c * S);
            v8[jj] = f2bfu((v - mu) * r * w[c] + b[c]);
        }
        *reinterpret_cast<uint4*>(op + q * 8) = *reinterpret_cast<uint4*>(v8);
    }
}

// ---------------- transpose [Cc][S] -> [S][Cc] -------------------------------
__global__ __launch_bounds__(BLK) void k_tr(const bft* __restrict__ in,
                                            bft* __restrict__ out) {
    __shared__ unsigned short t[32][72];
    const int tid = threadIdx.x;
    const int s0 = blockIdx.x * 64, c0 = blockIdx.y * 32;
    {
        int c = tid >> 3, sc = (tid & 7) * 8;
        *reinterpret_cast<uint4*>(&t[c][sc]) =
            *reinterpret_cast<const uint4*>(in + (size_t)(c0 + c) * S + s0 + sc);
    }
    __syncthreads();
    {
        int s = tid >> 2, cc = (tid & 3) * 8;
        unsigned short v[8];
#pragma unroll
        for (int q = 0; q < 8; ++q) v[q] = t[cc + q][s];
        *reinterpret_cast<uint4*>(out + (size_t)(s0 + s) * Cc + c0 + cc) =
            *reinterpret_cast<uint4*>(v);
    }
}

// =============================================================================
// Unified MFMA bf16 GEMM. Block = (WR*FM*16) x (WC*FN*16), 4 waves (WR x WC),
// K-step = KSTEP (64 for row-major B, 32 for legacy).
//   BMODE: 0 = legacy col-major [k][n] scalar stage (KSTEP=32, BN=128);
//          2 = row-major [n][k] vector stage; 3 = strip row map into z^T [S][Cc]
//   OMODE: 0 = linear; 1 = FFN strip scatter; 2 = window-tiled -> spatial;
//          3 = transposed packed: idx = n*strideO + m, 8B stores
// =============================================================================
template <int WR, int WC, int FM, int FN, int KSTEP, int BMODE, int OMODE,
          bool HASBIAS, bool HASRES, typename OutT, typename ResT>
__global__ __launch_bounds__(256) void k_mm(
    const bft* __restrict__ A, int strideA, int Mreal, long zA,
    const bft* __restrict__ B, int strideB, long zB,
    OutT* __restrict__ Out, int strideO, long zO,
    const float* __restrict__ bias,
    const ResT* __restrict__ Res, long zR,
    int K, int w0) {
    static_assert(BMODE != 0 || KSTEP == 32, "legacy B needs KSTEP 32");
    constexpr int BM = WR * FM * 16, BN = WC * FN * 16;
    constexpr int AV = KSTEP / 8;                 // uint4 per row
    __shared__ unsigned short Al[BM][KSTEP + 8];
    __shared__ unsigned short Bl[BN][KSTEP + 8];
    const int tid = threadIdx.x;
    const int n0 = blockIdx.x * BN, m0 = blockIdx.y * BM, bz = blockIdx.z;
    const int lane = tid & 63, wv = tid >> 6;
    const int wr = wv / WC, wc = wv % WC;
    const int l15 = lane & 15, l4 = lane >> 4;
    f32x4 acc[FM][FN] = {};

    const bft* Ab = A + (size_t)bz * zA;
    const bft* Bb = B + (size_t)bz * zB;

    for (int k0 = 0; k0 < K; k0 += KSTEP) {
        // ---- stage A (row-major, vectorized)
        for (int id = tid; id < BM * AV; id += 256) {
            int row = id / AV, kc = (id % AV) * 8;
            int gm = m0 + row; if (gm >= Mreal) gm = Mreal - 1;
            *reinterpret_cast<uint4*>(&Al[row][kc]) =
                *reinterpret_cast<const uint4*>(Ab + (size_t)gm * strideA + k0 + kc);
        }
        // ---- stage B
        if constexpr (BMODE == 0) {
            int bn = tid & 127, bk = (tid >> 7) * 16;
            unsigned short v[16];
            const bft* src = Bb + (size_t)(k0 + bk) * strideB + n0 + bn;
#pragma unroll
            for (int e = 0; e < 16; ++e) v[e] = bfu(src + (size_t)e * strideB);
#pragma unroll
            for (int q = 0; q < 2; ++q)
                *reinterpret_cast<uint4*>(&Bl[bn][bk + 8 * q]) =
                    *reinterpret_cast<uint4*>(&v[8 * q]);
        } else {
            for (int id = tid; id < BN * AV; id += 256) {
                int row = id / AV, kc = (id % AV) * 8;
                uint4 val;
                if constexpr (BMODE == 2) {
                    val = *reinterpret_cast<const uint4*>(
                        Bb + (size_t)(n0 + row) * strideB + k0 + kc);
                } else {  // BMODE 3
                    int gn = n0 + row;
                    int h = gn / PW, wl = gn - h * PW;
                    int wg = w0 - 1 + wl;
                    if (wg >= 0 && wg < L)
                        val = *reinterpret_cast<const uint4*>(
                            Bb + (size_t)(h * L + wg) * Cc + k0 + kc);
                    else
                        val = make_uint4(0, 0, 0, 0);
                }
                *reinterpret_cast<uint4*>(&Bl[row][kc]) = val;
            }
        }
        __syncthreads();
#pragma unroll
        for (int kk = 0; kk < KSTEP / 32; ++kk) {
            bf16x8 af[FM], bf[FN];
#pragma unroll
            for (int i = 0; i < FM; ++i)
                af[i] = *reinterpret_cast<const bf16x8*>(
                    &Al[wr * FM * 16 + i * 16 + l15][kk * 32 + l4 * 8]);
#pragma unroll
            for (int j = 0; j < FN; ++j)
                bf[j] = *reinterpret_cast<const bf16x8*>(
                    &Bl[wc * FN * 16 + j * 16 + l15][kk * 32 + l4 * 8]);
#pragma unroll
            for (int i = 0; i < FM; ++i)
#pragma unroll
                for (int j = 0; j < FN; ++j)
                    acc[i][j] = __builtin_amdgcn_mfma_f32_16x16x32_bf16(
                        af[i], bf[j], acc[i][j], 0, 0, 0);
        }
        __syncthreads();
    }
    if constexpr (OMODE == 3) {
#pragma unroll
        for (int i = 0; i < FM; ++i) {
            int mB = m0 + wr * FM * 16 + i * 16 + l4 * 4;
#pragma unroll
            for (int j = 0; j < FN; ++j) {
                int n = n0 + wc * FN * 16 + j * 16 + l15;
                unsigned short v[4];
#pragma unroll
                for (int r = 0; r < 4; ++r) v[r] = f2bfu(acc[i][j][r]);
                *reinterpret_cast<uint2*>((bft*)Out + (size_t)bz * zO
                    + (size_t)n * strideO + mB) = *reinterpret_cast<uint2*>(v);
            }
        }
        return;
    }
#pragma unroll
    for (int i = 0; i < FM; ++i) {
        int mB = m0 + wr * FM * 16 + i * 16 + l4 * 4;
#pragma unroll
        for (int j = 0; j < FN; ++j) {
            int n = n0 + wc * FN * 16 + j * 16 + l15;
#pragma unroll
            for (int r = 0; r < 4; ++r) {
                int m = mB + r;
                if (m >= Mreal) continue;
                float vv = acc[i][j][r];
                if constexpr (HASBIAS) vv += bias[m];
                size_t idx;
                if constexpr (OMODE == 0)
                    idx = (size_t)bz * zO + (size_t)m * strideO + n;
                else if constexpr (OMODE == 1) {
                    int h = n / SW, wl = n - h * SW;
                    idx = (size_t)m * S + (size_t)h * L + w0 + wl;
                } else {
                    int win = n >> 6, e = n & 63;
                    int hh = ((win / 24) << 3) + (e >> 3);
                    int ww = ((win % 24) << 3) + (e & 7);
                    idx = (size_t)m * S + (size_t)hh * L + ww;
                }
                if constexpr (HASRES) vv += ldf(Res + ((OMODE == 0)
                                  ? ((size_t)bz * zR + (size_t)m * strideO + n) : idx));
                stf(Out + idx, vv);
            }
        }
    }
}

// ---------------- depthwise 3x3 (8 outputs/thread) -> window-tiled -----------
__global__ __launch_bounds__(BLK) void k_dwconv(const bft* __restrict__ in,
                                                const float* __restrict__ wt,
                                                bft* __restrict__ out) {
    int t = blockIdx.x * BLK + threadIdx.x;      // [0, Cc*S/8)
    int ch = t / (S / 8);
    int rem = t - ch * (S / 8);
    int h = rem / 24, wb = (rem - h * 24) * 8;
    const float* wp = wt + (size_t)ch * 9;
    const bft* ip = in + (size_t)ch * S;
    float acc[8] = {};
#pragma unroll
    for (int dy = -1; dy <= 1; ++dy) {
        int hh = h + dy;
        if (hh < 0 || hh >= L) continue;
        const bft* rp = ip + hh * L + wb;
        float e[10];
        uint4 mid = *reinterpret_cast<const uint4*>(rp);
        const unsigned short* ms = reinterpret_cast<const unsigned short*>(&mid);
#pragma unroll
        for (int q = 0; q < 8; ++q) e[q + 1] = bu2f(ms[q]);
        e[0] = (wb > 0) ? ldf(rp - 1) : 0.f;
        e[9] = (wb + 8 < L) ? ldf(rp + 8) : 0.f;
        float c0 = wp[(dy + 1) * 3], c1 = wp[(dy + 1) * 3 + 1], c2 = wp[(dy + 1) * 3 + 2];
#pragma unroll
        for (int q = 0; q < 8; ++q)
            acc[q] += c0 * e[q] + c1 * e[q + 1] + c2 * e[q + 2];
    }
    int win = (h >> 3) * 24 + (wb >> 3);
    int e0 = (h & 7) * 8;
    unsigned short ov[8];
#pragma unroll
    for (int q = 0; q < 8; ++q) ov[q] = f2bfu(acc[q]);
    *reinterpret_cast<uint4*>(out + (size_t)ch * S + win * 64 + e0) =
        *reinterpret_cast<uint4*>(ov);
}

// ---------------- window channel attention via MFMA; out = [s*][Cc] ----------
__global__ __launch_bounds__(256) void k_attn_mfma(const bft* __restrict__ QW,
                                                   const bft* __restrict__ KW,
                                                   const bft* __restrict__ VW,
                                                   const float* __restrict__ temp,
                                                   bft* __restrict__ outp) {
    __shared__ unsigned short qls[4][32 * 66];
    __shared__ unsigned short kls[4][32 * 66];
    __shared__ unsigned short vls[4][32 * 66];
    __shared__ float rqs[4][32], rks[4][32];
    const int tid = threadIdx.x;
    const int wv = tid >> 6, lane = tid & 63;
    const int win = blockIdx.x * 4 + wv;
    const int hd = blockIdx.y;
    const int l15 = lane & 15, l4 = lane >> 4;
    unsigned short* ql = qls[wv];
    unsigned short* kl = kls[wv];
    unsigned short* vl = vls[wv];
    const size_t base = (size_t)(hd * 32) * S + (size_t)win * 64;

#pragma unroll
    for (int i = 0; i < 4; ++i) {
        int c = i * 8 + (lane >> 3), e0 = (lane & 7) * 8;
        size_t g = base + (size_t)c * S + e0;
        uint4 vq = *reinterpret_cast<const uint4*>(QW + g);
        uint4 vk = *reinterpret_cast<const uint4*>(KW + g);
        uint4 vvv = *reinterpret_cast<const uint4*>(VW + g);
        unsigned int* dq = reinterpret_cast<unsigned int*>(&ql[c * 66 + e0]);
        unsigned int* dk = reinterpret_cast<unsigned int*>(&kl[c * 66 + e0]);
        unsigned int* dv = reinterpret_cast<unsigned int*>(&vl[c * 66 + e0]);
        dq[0] = vq.x; dq[1] = vq.y; dq[2] = vq.z; dq[3] = vq.w;
        dk[0] = vk.x; dk[1] = vk.y; dk[2] = vk.z; dk[3] = vk.w;
        dv[0] = vvv.x; dv[1] = vvv.y; dv[2] = vvv.z; dv[3] = vvv.w;
    }
    __syncthreads();
    {
        int row = lane & 31;
        const unsigned short* src = (lane < 32) ? ql : kl;
        float s = 0.f;
#pragma unroll
        for (int w = 0; w < 32; ++w) {
            unsigned int d = *reinterpret_cast<const unsigned int*>(&src[row * 66 + 2 * w]);
            float a = bu2f((unsigned short)(d & 0xffff));
            float b = bu2f((unsigned short)(d >> 16));
            s += a * a + b * b;
        }
        float r = 1.f / fmaxf(sqrtf(s), 1e-12f);
        if (lane < 32) rqs[wv][row] = r; else rks[wv][row] = r;
    }
    __syncthreads();
    f32x4 at[2][2] = {};
#pragma unroll
    for (int ks = 0; ks < 2; ++ks) {
        bf16x8 aq[2], bk[2];
#pragma unroll
        for (int i = 0; i < 2; ++i)
            aq[i] = ld8(&ql[(i * 16 + l15) * 66 + ks * 32 + l4 * 8]);
#pragma unroll
        for (int j = 0; j < 2; ++j)
            bk[j] = ld8(&kl[(j * 16 + l15) * 66 + ks * 32 + l4 * 8]);
#pragma unroll
        for (int i = 0; i < 2; ++i)
#pragma unroll
            for (int j = 0; j < 2; ++j)
                at[i][j] = __builtin_amdgcn_mfma_f32_16x16x32_bf16(
                    aq[i], bk[j], at[i][j], 0, 0, 0);
    }
    float tpr = temp[hd];
    float rk0 = rks[wv][l15] * tpr, rk1 = rks[wv][16 + l15] * tpr;
    float pr[2][2][4];
#pragma unroll
    for (int i = 0; i < 2; ++i)
#pragma unroll
        for (int r = 0; r < 4; ++r) {
            int c = i * 16 + l4 * 4 + r;
            float rq = rqs[wv][c];
            float v0 = at[i][0][r] * rq * rk0;
            float v1 = at[i][1][r] * rq * rk1;
            float mx = fmaxf(v0, v1);
#pragma unroll
            for (int m = 1; m < 16; m <<= 1) mx = fmaxf(mx, __shfl_xor(mx, m));
            v0 = __expf(v0 - mx);
            v1 = __expf(v1 - mx);
            float sm = v0 + v1;
#pragma unroll
            for (int m = 1; m < 16; m <<= 1) sm += __shfl_xor(sm, m);
            float inv = 1.f / sm;
            pr[i][0][r] = v0 * inv;
            pr[i][1][r] = v1 * inv;
        }
    __syncthreads();
    unsigned short* pl = ql;
#pragma unroll
    for (int i = 0; i < 2; ++i)
#pragma unroll
        for (int j = 0; j < 2; ++j)
#pragma unroll
            for (int r = 0; r < 4; ++r)
                pl[(i * 16 + l4 * 4 + r) * 34 + j * 16 + l15] = f2bfu(pr[i][j][r]);
    __syncthreads();
    bf16x8 ap[2];
#pragma unroll
    for (int i = 0; i < 2; ++i)
        ap[i] = ld8(&pl[(i * 16 + l15) * 34 + l4 * 8]);
    f32x4 o[2][4] = {};
#pragma unroll
    for (int j = 0; j < 4; ++j) {
        unsigned short tv[8];
#pragma unroll
        for (int q = 0; q < 8; ++q)
            tv[q] = vl[(l4 * 8 + q) * 66 + j * 16 + l15];
        bf16x8 bv = *reinterpret_cast<bf16x8*>(tv);
#pragma unroll
        for (int i = 0; i < 2; ++i)
            o[i][j] = __builtin_amdgcn_mfma_f32_16x16x32_bf16(ap[i], bv, o[i][j], 0, 0, 0);
    }
    // ---- restage O into dead kl/vl as [e][c_local] (stride 40, 16B-aligned)
#pragma unroll
    for (int i = 0; i < 2; ++i)
#pragma unroll
        for (int j = 0; j < 4; ++j) {
            int e = j * 16 + l15, cl = i * 16 + l4 * 4;
            unsigned short v[4];
#pragma unroll
            for (int r = 0; r < 4; ++r) v[r] = f2bfu(o[i][j][r]);
            unsigned short* row = ((e < 32) ? kl : vl) + (e & 31) * 40 + cl;
            *reinterpret_cast<uint2*>(row) = *reinterpret_cast<uint2*>(v);
        }
    // each lane writes one 64B contiguous [s*][c] row
    {
        const unsigned short* row = ((lane < 32) ? kl : vl) + (lane & 31) * 40;
        bft* dst = outp + (size_t)(win * 64 + lane) * Cc + hd * 32;
#pragma unroll
        for (int q = 0; q < 4; ++q)
            *reinterpret_cast<uint4*>(dst + q * 8) =
                *reinterpret_cast<const uint4*>(row + q * 8);
    }
}

// ---------------- FFN gate on strip (vectorized, 8 outputs/thread) -----------
__global__ __launch_bounds__(BLK) void k_gate(const bft* __restrict__ f,
                                              const float* __restrict__ wt,
                                              bft* __restrict__ g) {
    const int NS = L * PW, NG = L * SW;  // 9600, 9216
    int t = blockIdx.x * BLK + threadIdx.x;       // HID * L * 6
    int c = t / (L * 6);
    int rr = t - c * (L * 6);
    int h = rr / 6, wl0 = (rr - h * 6) * 8;
    const bft* f1 = f + (size_t)c * NS;
    const bft* f2 = f + (size_t)(c + HID) * NS;
    float w1[9], w2[9];
#pragma unroll
    for (int i = 0; i < 9; ++i) {
        w1[i] = wt[(size_t)c * 9 + i];
        w2[i] = wt[((size_t)c + HID) * 9 + i];
    }
    float a1[8], a2[8];
#pragma unroll
    for (int j = 0; j < 8; ++j) { a1[j] = 0.f; a2[j] = 0.f; }
#pragma unroll
    for (int dy = 0; dy < 3; ++dy) {
        int hh = h + dy - 1;
        if (hh < 0 || hh >= L) continue;
        float e1[10], e2[10];
        const unsigned int* p1 =
            reinterpret_cast<const unsigned int*>(f1 + (size_t)hh * PW + wl0);
        const unsigned int* p2 =
            reinterpret_cast<const unsigned int*>(f2 + (size_t)hh * PW + wl0);
#pragma unroll
        for (int q = 0; q < 5; ++q) {
            unsigned int d1 = p1[q], d2 = p2[q];
            e1[2 * q]     = bu2f((unsigned short)(d1 & 0xffff));
            e1[2 * q + 1] = bu2f((unsigned short)(d1 >> 16));
            e2[2 * q]     = bu2f((unsigned short)(d2 & 0xffff));
            e2[2 * q + 1] = bu2f((unsigned short)(d2 >> 16));
        }
#pragma unroll
        for (int dx = 0; dx < 3; ++dx) {
            float ww1 = w1[dy * 3 + dx], ww2 = w2[dy * 3 + dx];
#pragma unroll
            for (int j = 0; j < 8; ++j) {
                a1[j] += ww1 * e1[j + dx];
                a2[j] += ww2 * e2[j + dx];
            }
        }
    }
    unsigned short ov[8];
#pragma unroll
    for (int j = 0; j < 8; ++j) {
        float ge = 0.5f * a1[j] * (1.f + erff(a1[j] * 0.70710678118654752f));
        ov[j] = f2bfu(ge * a2[j]);
    }
    *reinterpret_cast<uint4*>(g + (size_t)c * NG + (size_t)h * SW + wl0) =
        *reinterpret_cast<uint4*>(ov);
}

// -----------------------------------------------------------------------------
extern "C" void kernel_launch(void* const* d_in, const int* in_sizes, int n_in,
                              void* d_out, int out_size, void* d_ws, size_t ws_size,
                              hipStream_t stream) {
    const float* x      = (const float*)d_in[0];
    const float* n1w    = (const float*)d_in[1];
    const float* n1b    = (const float*)d_in[2];
    const float* w_qkv  = (const float*)d_in[3];
    const float* w_dw   = (const float*)d_in[4];
    const float* temp   = (const float*)d_in[5];
    const float* w_proj = (const float*)d_in[6];
    const float* b_proj = (const float*)d_in[7];
    const float* n2w    = (const float*)d_in[8];
    const float* n2b    = (const float*)d_in[9];
    const float* w_in   = (const float*)d_in[10];
    const float* w_dwf  = (const float*)d_in[11];
    const float* w_out  = (const float*)d_in[12];
    float* outp = (float*)d_out;

    // workspace layout: 100,122,624 bytes (unchanged)
    const size_t DCT_B = 147456;
    const size_t CS    = (size_t)Cc * S;
    const size_t X1_B  = (size_t)Bn * CS * 2;
    const size_t P_B   = CS * 2;
    const size_t WB_B  = 884736;
    const size_t NEED  = DCT_B + X1_B + 2 * P_B + (size_t)3 * CS * 2 + WB_B;
    if (ws_size < NEED) return;

    char* p = (char*)d_ws;
    bft* dctb  = (bft*)p;
    bft* dctTb = dctb + L * L;
    p += DCT_B;
    bft* X1    = (bft*)p;                  p += X1_B;
    bft* Pb    = (bft*)p;                  p += P_B;
    bft* Qb    = (bft*)p;                  p += P_B;
    bft* QKV   = (bft*)p;                  p += 3 * CS * 2;
    bft* w_qkv_b = (bft*)p;
    bft* w_proj_b = w_qkv_b + 576 * 192;
    bft* w_in_b  = w_proj_b + 192 * 192;   // 1024x192 (pad M)
    bft* w_out_b = w_in_b + 1024 * 192;    // 192x512 (pad K)
    bft* fbuf  = QKV;                      // [1024][9600]
    bft* gstrip = Qb;                      // [512][9216]
    bft* attnT = QKV + CS;                 // [36864][192]

    k_dct_init<<<144, BLK, 0, stream>>>(dctb, dctTb);
    k_cvt<<<432, BLK, 0, stream>>>(w_qkv, w_qkv_b, 576, 192, 192);
    k_cvt<<<144, BLK, 0, stream>>>(w_proj, w_proj_b, 192, 192, 192);
    k_cvt<<<768, BLK, 0, stream>>>(w_in, w_in_b, 1020, 192, 192);
    k_cvt<<<384, BLK, 0, stream>>>(w_out, w_out_b, 192, 510, 512);

    for (int b = 0; b < Bn; ++b) {
        const float* xb = x + (size_t)b * CS;
        bft* x1b = X1 + (size_t)b * CS;
        // LN1 -> z1 NCHW (Pb)
        k_ln8<float><<<S * 8 / BLK, BLK, 0, stream>>>(xb, n1w, n1b, Pb);
        // G1 (per c): D[h][p] = z1_c . dctb^T -> Tt[p][h] (Qb, OMODE3)
        k_mm<2, 2, 2, 6, 64, 2, 3, false, false, bft, float><<<dim3(1, 3, Cc), 256, 0, stream>>>(
            Pb, L, L, S,  dctb, L, 0,  Qb, L, S,  nullptr, nullptr, 0,  L, 0);
        // G2 (per c): D[p][q] = Tt_c . dctb^T -> yd[c][q*192+p] (Pb, OMODE3)
        k_mm<2, 2, 2, 6, 64, 2, 3, false, false, bft, float><<<dim3(1, 3, Cc), 256, 0, stream>>>(
            Qb, L, L, S,  dctb, L, 0,  Pb, L, S,  nullptr, nullptr, 0,  L, 0);
        // transpose yd -> ydT [s'][c] (Qb)
        k_tr<<<dim3(576, 6), BLK, 0, stream>>>(Pb, Qb);
        // qkv = W_qkv . ydT^T -> QKV [576][S]
        k_mm<2, 2, 4, 4, 64, 2, 0, false, false, bft, float><<<dim3(288, 5, 1), 256, 0, stream>>>(
            w_qkv_b, Cc, 576, 0,  Qb, Cc, 0,  QKV, S, 0,  nullptr, nullptr, 0,  Cc, 0);
        // depthwise 3x3 -> window-tiled: q->Pb, k->Qb, v->QKV[0:CS]
        k_dwconv<<<(Cc * S / 8) / BLK, BLK, 0, stream>>>(QKV, w_dw, Pb);
        k_dwconv<<<(Cc * S / 8) / BLK, BLK, 0, stream>>>(QKV + CS, w_dw + Cc * 9, Qb);
        k_dwconv<<<(Cc * S / 8) / BLK, BLK, 0, stream>>>(QKV + 2 * CS, w_dw + 2 * Cc * 9, QKV);
        // attention -> attnT [s*][c]
        k_attn_mfma<<<dim3(144, 6), 256, 0, stream>>>(Pb, Qb, QKV, temp, attnT);
        // proj + bias; B=attnT rows; window-decode epilogue -> Pb NCHW
        k_mm<2, 2, 4, 4, 64, 2, 2, true, false, bft, float><<<dim3(288, 2, 1), 256, 0, stream>>>(
            w_proj_b, Cc, Cc, 0,  attnT, Cc, 0,  Pb, S, 0,  b_proj, nullptr, 0,  Cc, 0);
        // G3 (per c): D[q][w'] = P_c . dctTb^T -> Ut[w'][q] (Qb, OMODE3)
        k_mm<2, 2, 2, 6, 64, 2, 3, false, false, bft, float><<<dim3(1, 3, Cc), 256, 0, stream>>>(
            Pb, L, L, S,  dctTb, L, 0,  Qb, L, S,  nullptr, nullptr, 0,  L, 0);
        // G4 (per c): D[h'][w'] = dctTb . Ut^T + x -> x1 NCHW
        k_mm<2, 2, 2, 6, 64, 2, 0, false, true, bft, float><<<dim3(1, 3, Cc), 256, 0, stream>>>(
            dctTb, L, L, 0,  Qb, L, S,  x1b, L, S,  nullptr, xb, S,  L, 0);
    }
    for (int b = 0; b < Bn; ++b) {
        bft* x1b = X1 + (size_t)b * CS;
        float* outb = outp + (size_t)b * CS;
        // LN2 -> z^T [s][c] (Pb)
        k_lnT8<bft><<<S * 8 / BLK, BLK, 0, stream>>>(x1b, n2w, n2b, Pb);
        for (int st = 0; st < 4; ++st) {
            int w0 = st * SW;
            // f = W_in . z (strip rows of z^T) -> fbuf [1024][9600]
            k_mm<2, 2, 4, 4, 64, 3, 0, false, false, bft, float><<<dim3(75, 8, 1), 256, 0, stream>>>(
                w_in_b, Cc, 1024, 0,  Pb, Cc, 0,  fbuf, L * PW, 0,
                nullptr, nullptr, 0,  Cc, w0);
            // gated dwconv + GELU
            k_gate<<<(HID * L * 6) / BLK, BLK, 0, stream>>>(fbuf, w_dwf, gstrip);
            // out = W_out . g + x1 (legacy col-stage B, strip scatter)
            k_mm<2, 2, 4, 4, 32, 0, 1, false, true, float, bft><<<dim3(72, 2, 1), 256, 0, stream>>>(
                w_out_b, 512, Cc, 0,  gstrip, L * SW, 0,  outb, 0, 0,
                nullptr, x1b, 0,  512, w0);
        }
    }
}

// Round 11
// 963.566 us; speedup vs baseline: 1.0832x; 1.0624x over previous
//
#include <hip/hip_runtime.h>
#include <hip/hip_bf16.h>

typedef __hip_bfloat16 bft;
typedef __attribute__((ext_vector_type(8))) short bf16x8;
typedef __attribute__((ext_vector_type(4))) float f32x4;

#define BLK 256
static constexpr int Cc = 192;     // channels
static constexpr int L  = 192;     // H = W
static constexpr int S  = 36864;   // L*L
static constexpr int Bn = 2;       // batch
static constexpr int HID = 510;    // int(192*2.66)
static constexpr int CH = 64;      // FFN chunk height (image rows)
static constexpr int FTR = (CH + 2) * L;   // 12672 fT rows (with halo)
static constexpr int GTR = CH * L;         // 12288 gT rows
static constexpr double PI_D = 3.141592653589793238462643383279502884;

__device__ __forceinline__ float ldf(const float* p) { return *p; }
__device__ __forceinline__ float ldf(const bft* p)   { return __bfloat162float(*p); }
__device__ __forceinline__ void  stf(float* p, float v) { *p = v; }
__device__ __forceinline__ void  stf(bft* p, float v)   { *p = __float2bfloat16(v); }
__device__ __forceinline__ unsigned short f2bfu(float f) {
    bft h = __float2bfloat16(f);
    return *reinterpret_cast<const unsigned short*>(&h);
}
__device__ __forceinline__ unsigned short bfu(const bft* p) {
    return *reinterpret_cast<const unsigned short*>(p);
}
__device__ __forceinline__ float bu2f(unsigned short u) {
    unsigned int x = (unsigned int)u << 16;
    return __uint_as_float(x);
}
__device__ __forceinline__ bf16x8 ld8(const unsigned short* p) {   // 4B-aligned
    union { unsigned int u[4]; bf16x8 v; } t;
    const unsigned int* q = reinterpret_cast<const unsigned int*>(p);
    t.u[0] = q[0]; t.u[1] = q[1]; t.u[2] = q[2]; t.u[3] = q[3];
    return t.v;
}

// ---------------- DCT matrix init -> bf16 direct + transposed ----------------
__global__ __launch_bounds__(BLK) void k_dct_init(bft* __restrict__ dctb,
                                                  bft* __restrict__ dctTb) {
    int idx = blockIdx.x * BLK + threadIdx.x;
    if (idx >= L * L) return;
    int p = idx / L, h = idx - p * L;
    double v = (p == 0) ? sqrt(1.0 / L)
                        : cos(PI_D * p * (2 * h + 1) / (2.0 * L)) * sqrt(2.0 / L);
    bft bv = __float2bfloat16((float)v);
    dctb[p * L + h] = bv;
    dctTb[h * L + p] = bv;
}

// ---------------- fp32 weight -> bf16 with zero pad --------------------------
__global__ __launch_bounds__(BLK) void k_cvt(const float* __restrict__ src,
                                             bft* __restrict__ dst,
                                             int Mr, int Kr, int Kp) {
    int idx = blockIdx.x * BLK + threadIdx.x;
    int m = idx / Kp, k = idx - m * Kp;
    float v = (m < Mr && k < Kr) ? src[(size_t)m * Kr + k] : 0.f;
    dst[idx] = __float2bfloat16(v);
}

// ---------------- w_in -> bf16, rows remapped: f1 at 0..509, f2 at 512..1021 -
__global__ __launch_bounds__(BLK) void k_cvt_ffn(const float* __restrict__ src,
                                                 bft* __restrict__ dst) {
    int idx = blockIdx.x * BLK + threadIdx.x;   // [0, 1024*192)
    int m = idx / Cc, k = idx - m * Cc;
    float v = 0.f;
    if (m < 510) v = src[(size_t)m * Cc + k];
    else if (m >= 512 && m < 1022) v = src[(size_t)(m - 2) * Cc + k];
    dst[idx] = __float2bfloat16(v);
}

// ---------------- LayerNorm, 8 lanes/pixel, NCHW out -------------------------
template <typename TI>
__global__ __launch_bounds__(BLK) void k_ln8(const TI* __restrict__ x,
                                             const float* __restrict__ w,
                                             const float* __restrict__ b,
                                             bft* __restrict__ out) {
    int t = blockIdx.x * BLK + threadIdx.x;
    int s = t >> 3, u = t & 7;
    const TI* xp = x + s;
    float sum = 0.f, sq = 0.f;
#pragma unroll
    for (int j = 0; j < 24; ++j) {
        float v = ldf(xp + (size_t)(u * 24 + j) * S);
        sum += v; sq += v * v;
    }
#pragma unroll
    for (int m = 1; m < 8; m <<= 1) {
        sum += __shfl_xor(sum, m);
        sq  += __shfl_xor(sq, m);
    }
    float mu = sum * (1.f / Cc);
    float var = sq * (1.f / Cc) - mu * mu;
    float r = rsqrtf(var + 1e-5f);
#pragma unroll
    for (int j = 0; j < 24; ++j) {
        int c = u * 24 + j;
        float v = ldf(xp + (size_t)c * S);
        stf(out + (size_t)c * S + s, (v - mu) * r * w[c] + b[c]);
    }
}

// ---------------- LayerNorm, 8 lanes/pixel, transposed out z^T [s][c] --------
template <typename TI>
__global__ __launch_bounds__(BLK) void k_lnT8(const TI* __restrict__ x,
                                              const float* __restrict__ w,
                                              const float* __restrict__ b,
                                              bft* __restrict__ out) {
    int t = blockIdx.x * BLK + threadIdx.x;
    int s = t >> 3, u = t & 7;
    const TI* xp = x + s;
    float sum = 0.f, sq = 0.f;
#pragma unroll
    for (int j = 0; j < 24; ++j) {
        float v = ldf(xp + (size_t)(u * 24 + j) * S);
        sum += v; sq += v * v;
    }
#pragma unroll
    for (int m = 1; m < 8; m <<= 1) {
        sum += __shfl_xor(sum, m);
        sq  += __shfl_xor(sq, m);
    }
    float mu = sum * (1.f / Cc);
    float var = sq * (1.f / Cc) - mu * mu;
    float r = rsqrtf(var + 1e-5f);
    bft* op = out + (size_t)s * Cc + u * 24;
#pragma unroll
    for (int q = 0; q < 3; ++q) {
        unsigned short v8[8];
#pragma unroll
        for (int jj = 0; jj < 8; ++jj) {
            int c = u * 24 + q * 8 + jj;
            float v = ldf(xp + (size_t)c * S);
            v8[jj] = f2bfu((v - mu) * r * w[c] + b[c]);
        }
        *reinterpret_cast<uint4*>(op + q * 8) = *reinterpret_cast<uint4*>(v8);
    }
}

// ---------------- transpose [Cc][S] -> [S][Cc] -------------------------------
__global__ __launch_bounds__(BLK) void k_tr(const bft* __restrict__ in,
                                            bft* __restrict__ out) {
    __shared__ unsigned short t[32][72];
    const int tid = threadIdx.x;
    const int s0 = blockIdx.x * 64, c0 = blockIdx.y * 32;
    {
        int c = tid >> 3, sc = (tid & 7) * 8;
        *reinterpret_cast<uint4*>(&t[c][sc]) =
            *reinterpret_cast<const uint4*>(in + (size_t)(c0 + c) * S + s0 + sc);
    }
    __syncthreads();
    {
        int s = tid >> 2, cc = (tid & 3) * 8;
        unsigned short v[8];
#pragma unroll
        for (int q = 0; q < 8; ++q) v[q] = t[cc + q][s];
        *reinterpret_cast<uint4*>(out + (size_t)(s0 + s) * Cc + c0 + cc) =
            *reinterpret_cast<uint4*>(v);
    }
}

// =============================================================================
// Unified MFMA bf16 GEMM. Block = (WR*FM*16) x (WC*FN*16), 4 waves (WR x WC).
//   BMODE: 0 = legacy col-major [k][n] scalar stage (KSTEP=32);
//          2 = row-major [n][k]; 4 = row-major with row-range mask [rlo,rhi)
//   OMODE: 0 = linear; 2 = window-tiled -> spatial; 3 = transposed packed
// =============================================================================
template <int WR, int WC, int FM, int FN, int KSTEP, int BMODE, int OMODE,
          bool HASBIAS, bool HASRES, typename OutT, typename ResT>
__global__ __launch_bounds__(256) void k_mm(
    const bft* __restrict__ A, int strideA, int Mreal, long zA,
    const bft* __restrict__ B, int strideB, long zB,
    OutT* __restrict__ Out, int strideO, long zO,
    const float* __restrict__ bias,
    const ResT* __restrict__ Res, long zR,
    int K, int rlo, int rhi) {
    static_assert(BMODE != 0 || KSTEP == 32, "legacy B needs KSTEP 32");
    constexpr int BM = WR * FM * 16, BN = WC * FN * 16;
    constexpr int AV = KSTEP / 8;
    __shared__ unsigned short Al[BM][KSTEP + 8];
    __shared__ unsigned short Bl[BN][KSTEP + 8];
    const int tid = threadIdx.x;
    const int n0 = blockIdx.x * BN, m0 = blockIdx.y * BM, bz = blockIdx.z;
    const int lane = tid & 63, wv = tid >> 6;
    const int wr = wv / WC, wc = wv % WC;
    const int l15 = lane & 15, l4 = lane >> 4;
    f32x4 acc[FM][FN] = {};

    const bft* Ab = A + (size_t)bz * zA;
    const bft* Bb = B + (size_t)bz * zB;

    for (int k0 = 0; k0 < K; k0 += KSTEP) {
        for (int id = tid; id < BM * AV; id += 256) {
            int row = id / AV, kc = (id % AV) * 8;
            int gm = m0 + row; if (gm >= Mreal) gm = Mreal - 1;
            *reinterpret_cast<uint4*>(&Al[row][kc]) =
                *reinterpret_cast<const uint4*>(Ab + (size_t)gm * strideA + k0 + kc);
        }
        if constexpr (BMODE == 0) {
            int bn = tid & 127, bk = (tid >> 7) * 16;
            unsigned short v[16];
            const bft* src = Bb + (size_t)(k0 + bk) * strideB + n0 + bn;
#pragma unroll
            for (int e = 0; e < 16; ++e) v[e] = bfu(src + (size_t)e * strideB);
#pragma unroll
            for (int q = 0; q < 2; ++q)
                *reinterpret_cast<uint4*>(&Bl[bn][bk + 8 * q]) =
                    *reinterpret_cast<uint4*>(&v[8 * q]);
        } else {
            for (int id = tid; id < BN * AV; id += 256) {
                int row = id / AV, kc = (id % AV) * 8;
                int gn = n0 + row;
                uint4 val;
                if constexpr (BMODE == 2) {
                    val = *reinterpret_cast<const uint4*>(
                        Bb + (size_t)gn * strideB + k0 + kc);
                } else {  // BMODE 4: masked row range
                    if (gn >= rlo && gn < rhi)
                        val = *reinterpret_cast<const uint4*>(
                            Bb + (size_t)gn * strideB + k0 + kc);
                    else
                        val = make_uint4(0, 0, 0, 0);
                }
                *reinterpret_cast<uint4*>(&Bl[row][kc]) = val;
            }
        }
        __syncthreads();
#pragma unroll
        for (int kk = 0; kk < KSTEP / 32; ++kk) {
            bf16x8 af[FM], bf[FN];
#pragma unroll
            for (int i = 0; i < FM; ++i)
                af[i] = *reinterpret_cast<const bf16x8*>(
                    &Al[wr * FM * 16 + i * 16 + l15][kk * 32 + l4 * 8]);
#pragma unroll
            for (int j = 0; j < FN; ++j)
                bf[j] = *reinterpret_cast<const bf16x8*>(
                    &Bl[wc * FN * 16 + j * 16 + l15][kk * 32 + l4 * 8]);
#pragma unroll
            for (int i = 0; i < FM; ++i)
#pragma unroll
                for (int j = 0; j < FN; ++j)
                    acc[i][j] = __builtin_amdgcn_mfma_f32_16x16x32_bf16(
                        af[i], bf[j], acc[i][j], 0, 0, 0);
        }
        __syncthreads();
    }
    if constexpr (OMODE == 3) {
#pragma unroll
        for (int i = 0; i < FM; ++i) {
            int mB = m0 + wr * FM * 16 + i * 16 + l4 * 4;
#pragma unroll
            for (int j = 0; j < FN; ++j) {
                int n = n0 + wc * FN * 16 + j * 16 + l15;
                unsigned short v[4];
#pragma unroll
                for (int r = 0; r < 4; ++r) v[r] = f2bfu(acc[i][j][r]);
                *reinterpret_cast<uint2*>((bft*)Out + (size_t)bz * zO
                    + (size_t)n * strideO + mB) = *reinterpret_cast<uint2*>(v);
            }
        }
        return;
    }
#pragma unroll
    for (int i = 0; i < FM; ++i) {
        int mB = m0 + wr * FM * 16 + i * 16 + l4 * 4;
#pragma unroll
        for (int j = 0; j < FN; ++j) {
            int n = n0 + wc * FN * 16 + j * 16 + l15;
#pragma unroll
            for (int r = 0; r < 4; ++r) {
                int m = mB + r;
                if (m >= Mreal) continue;
                float vv = acc[i][j][r];
                if constexpr (HASBIAS) vv += bias[m];
                size_t idx;
                if constexpr (OMODE == 0)
                    idx = (size_t)bz * zO + (size_t)m * strideO + n;
                else {
                    int win = n >> 6, e = n & 63;
                    int hh = ((win / 24) << 3) + (e >> 3);
                    int ww = ((win % 24) << 3) + (e & 7);
                    idx = (size_t)m * S + (size_t)hh * L + ww;
                }
                if constexpr (HASRES) vv += ldf(Res + ((OMODE == 0)
                                  ? ((size_t)bz * zR + (size_t)m * strideO + n) : idx));
                stf(Out + idx, vv);
            }
        }
    }
}

// ---------------- depthwise 3x3 (8 outputs/thread) -> window-tiled -----------
__global__ __launch_bounds__(BLK) void k_dwconv(const bft* __restrict__ in,
                                                const float* __restrict__ wt,
                                                bft* __restrict__ out) {
    int t = blockIdx.x * BLK + threadIdx.x;
    int ch = t / (S / 8);
    int rem = t - ch * (S / 8);
    int h = rem / 24, wb = (rem - h * 24) * 8;
    const float* wp = wt + (size_t)ch * 9;
    const bft* ip = in + (size_t)ch * S;
    float acc[8] = {};
#pragma unroll
    for (int dy = -1; dy <= 1; ++dy) {
        int hh = h + dy;
        if (hh < 0 || hh >= L) continue;
        const bft* rp = ip + hh * L + wb;
        float e[10];
        uint4 mid = *reinterpret_cast<const uint4*>(rp);
        const unsigned short* ms = reinterpret_cast<const unsigned short*>(&mid);
#pragma unroll
        for (int q = 0; q < 8; ++q) e[q + 1] = bu2f(ms[q]);
        e[0] = (wb > 0) ? ldf(rp - 1) : 0.f;
        e[9] = (wb + 8 < L) ? ldf(rp + 8) : 0.f;
        float c0 = wp[(dy + 1) * 3], c1 = wp[(dy + 1) * 3 + 1], c2 = wp[(dy + 1) * 3 + 2];
#pragma unroll
        for (int q = 0; q < 8; ++q)
            acc[q] += c0 * e[q] + c1 * e[q + 1] + c2 * e[q + 2];
    }
    int win = (h >> 3) * 24 + (wb >> 3);
    int e0 = (h & 7) * 8;
    unsigned short ov[8];
#pragma unroll
    for (int q = 0; q < 8; ++q) ov[q] = f2bfu(acc[q]);
    *reinterpret_cast<uint4*>(out + (size_t)ch * S + win * 64 + e0) =
        *reinterpret_cast<uint4*>(ov);
}

// ---------------- window channel attention via MFMA; out = [s*][Cc] ----------
__global__ __launch_bounds__(256) void k_attn_mfma(const bft* __restrict__ QW,
                                                   const bft* __restrict__ KW,
                                                   const bft* __restrict__ VW,
                                                   const float* __restrict__ temp,
                                                   bft* __restrict__ outp) {
    __shared__ unsigned short qls[4][32 * 66];
    __shared__ unsigned short kls[4][32 * 66];
    __shared__ unsigned short vls[4][32 * 66];
    __shared__ float rqs[4][32], rks[4][32];
    const int tid = threadIdx.x;
    const int wv = tid >> 6, lane = tid & 63;
    const int win = blockIdx.x * 4 + wv;
    const int hd = blockIdx.y;
    const int l15 = lane & 15, l4 = lane >> 4;
    unsigned short* ql = qls[wv];
    unsigned short* kl = kls[wv];
    unsigned short* vl = vls[wv];
    const size_t base = (size_t)(hd * 32) * S + (size_t)win * 64;

#pragma unroll
    for (int i = 0; i < 4; ++i) {
        int c = i * 8 + (lane >> 3), e0 = (lane & 7) * 8;
        size_t g = base + (size_t)c * S + e0;
        uint4 vq = *reinterpret_cast<const uint4*>(QW + g);
        uint4 vk = *reinterpret_cast<const uint4*>(KW + g);
        uint4 vvv = *reinterpret_cast<const uint4*>(VW + g);
        unsigned int* dq = reinterpret_cast<unsigned int*>(&ql[c * 66 + e0]);
        unsigned int* dk = reinterpret_cast<unsigned int*>(&kl[c * 66 + e0]);
        unsigned int* dv = reinterpret_cast<unsigned int*>(&vl[c * 66 + e0]);
        dq[0] = vq.x; dq[1] = vq.y; dq[2] = vq.z; dq[3] = vq.w;
        dk[0] = vk.x; dk[1] = vk.y; dk[2] = vk.z; dk[3] = vk.w;
        dv[0] = vvv.x; dv[1] = vvv.y; dv[2] = vvv.z; dv[3] = vvv.w;
    }
    __syncthreads();
    {
        int row = lane & 31;
        const unsigned short* src = (lane < 32) ? ql : kl;
        float s = 0.f;
#pragma unroll
        for (int w = 0; w < 32; ++w) {
            unsigned int d = *reinterpret_cast<const unsigned int*>(&src[row * 66 + 2 * w]);
            float a = bu2f((unsigned short)(d & 0xffff));
            float b = bu2f((unsigned short)(d >> 16));
            s += a * a + b * b;
        }
        float r = 1.f / fmaxf(sqrtf(s), 1e-12f);
        if (lane < 32) rqs[wv][row] = r; else rks[wv][row] = r;
    }
    __syncthreads();
    f32x4 at[2][2] = {};
#pragma unroll
    for (int ks = 0; ks < 2; ++ks) {
        bf16x8 aq[2], bk[2];
#pragma unroll
        for (int i = 0; i < 2; ++i)
            aq[i] = ld8(&ql[(i * 16 + l15) * 66 + ks * 32 + l4 * 8]);
#pragma unroll
        for (int j = 0; j < 2; ++j)
            bk[j] = ld8(&kl[(j * 16 + l15) * 66 + ks * 32 + l4 * 8]);
#pragma unroll
        for (int i = 0; i < 2; ++i)
#pragma unroll
            for (int j = 0; j < 2; ++j)
                at[i][j] = __builtin_amdgcn_mfma_f32_16x16x32_bf16(
                    aq[i], bk[j], at[i][j], 0, 0, 0);
    }
    float tpr = temp[hd];
    float rk0 = rks[wv][l15] * tpr, rk1 = rks[wv][16 + l15] * tpr;
    float pr[2][2][4];
#pragma unroll
    for (int i = 0; i < 2; ++i)
#pragma unroll
        for (int r = 0; r < 4; ++r) {
            int c = i * 16 + l4 * 4 + r;
            float rq = rqs[wv][c];
            float v0 = at[i][0][r] * rq * rk0;
            float v1 = at[i][1][r] * rq * rk1;
            float mx = fmaxf(v0, v1);
#pragma unroll
            for (int m = 1; m < 16; m <<= 1) mx = fmaxf(mx, __shfl_xor(mx, m));
            v0 = __expf(v0 - mx);
            v1 = __expf(v1 - mx);
            float sm = v0 + v1;
#pragma unroll
            for (int m = 1; m < 16; m <<= 1) sm += __shfl_xor(sm, m);
            float inv = 1.f / sm;
            pr[i][0][r] = v0 * inv;
            pr[i][1][r] = v1 * inv;
        }
    __syncthreads();
    unsigned short* pl = ql;
#pragma unroll
    for (int i = 0; i < 2; ++i)
#pragma unroll
        for (int j = 0; j < 2; ++j)
#pragma unroll
            for (int r = 0; r < 4; ++r)
                pl[(i * 16 + l4 * 4 + r) * 34 + j * 16 + l15] = f2bfu(pr[i][j][r]);
    __syncthreads();
    bf16x8 ap[2];
#pragma unroll
    for (int i = 0; i < 2; ++i)
        ap[i] = ld8(&pl[(i * 16 + l15) * 34 + l4 * 8]);
    f32x4 o[2][4] = {};
#pragma unroll
    for (int j = 0; j < 4; ++j) {
        unsigned short tv[8];
#pragma unroll
        for (int q = 0; q < 8; ++q)
            tv[q] = vl[(l4 * 8 + q) * 66 + j * 16 + l15];
        bf16x8 bv = *reinterpret_cast<bf16x8*>(tv);
#pragma unroll
        for (int i = 0; i < 2; ++i)
            o[i][j] = __builtin_amdgcn_mfma_f32_16x16x32_bf16(ap[i], bv, o[i][j], 0, 0, 0);
    }
#pragma unroll
    for (int i = 0; i < 2; ++i)
#pragma unroll
        for (int j = 0; j < 4; ++j) {
            int e = j * 16 + l15, cl = i * 16 + l4 * 4;
            unsigned short v[4];
#pragma unroll
            for (int r = 0; r < 4; ++r) v[r] = f2bfu(o[i][j][r]);
            unsigned short* row = ((e < 32) ? kl : vl) + (e & 31) * 40 + cl;
            *reinterpret_cast<uint2*>(row) = *reinterpret_cast<uint2*>(v);
        }
    {
        const unsigned short* row = ((lane < 32) ? kl : vl) + (lane & 31) * 40;
        bft* dst = outp + (size_t)(win * 64 + lane) * Cc + hd * 32;
#pragma unroll
        for (int q = 0; q < 4; ++q)
            *reinterpret_cast<uint4*>(dst + q * 8) =
                *reinterpret_cast<const uint4*>(row + q * 8);
    }
}

// ---------------- FFN gate (transposed): fT [FTR][1024] -> gT [GTR][512] -----
// block: 32 pixels x 8 ch-groups (64 channels); grid (GTR/32, 8)
__global__ __launch_bounds__(BLK) void k_gateT(const bft* __restrict__ fT,
                                               const float* __restrict__ wt,
                                               bft* __restrict__ gT) {
    __shared__ float w1s[64][9];
    __shared__ float w2s[64][9];
    const int tid = threadIdx.x;
    const int cbase = blockIdx.y * 64;
    for (int id = tid; id < 576; id += BLK) {
        int cl = id / 9, k = id - cl * 9;
        int c = cbase + cl;
        w1s[cl][k] = (c < HID) ? wt[(size_t)c * 9 + k] : 0.f;
        w2s[cl][k] = (c < HID) ? wt[(size_t)(c + HID) * 9 + k] : 0.f;
    }
    __syncthreads();
    int px = blockIdx.x * 32 + (tid >> 3);       // [0, GTR)
    int cgl = (tid & 7) * 8;                     // local channel offset
    int hc = px / L, w = px - hc * L;
    float a1[8] = {}, a2[8] = {};
#pragma unroll
    for (int dy = 0; dy < 3; ++dy) {
#pragma unroll
        for (int dx = 0; dx < 3; ++dx) {
            int ww = w + dx - 1;
            if (ww < 0 || ww >= L) continue;
            size_t frow = (size_t)((hc + dy) * L + ww) * 1024 + cbase + cgl;
            uint4 u1 = *reinterpret_cast<const uint4*>(fT + frow);
            uint4 u2 = *reinterpret_cast<const uint4*>(fT + frow + 512);
            const unsigned short* e1 = reinterpret_cast<const unsigned short*>(&u1);
            const unsigned short* e2 = reinterpret_cast<const unsigned short*>(&u2);
            int k = dy * 3 + dx;
#pragma unroll
            for (int j = 0; j < 8; ++j) {
                a1[j] += w1s[cgl + j][k] * bu2f(e1[j]);
                a2[j] += w2s[cgl + j][k] * bu2f(e2[j]);
            }
        }
    }
    unsigned short ov[8];
#pragma unroll
    for (int j = 0; j < 8; ++j) {
        float ge = 0.5f * a1[j] * (1.f + erff(a1[j] * 0.70710678118654752f));
        ov[j] = f2bfu(ge * a2[j]);
    }
    *reinterpret_cast<uint4*>(gT + (size_t)px * 512 + cbase + cgl) =
        *reinterpret_cast<uint4*>(ov);
}

// -----------------------------------------------------------------------------
extern "C" void kernel_launch(void* const* d_in, const int* in_sizes, int n_in,
                              void* d_out, int out_size, void* d_ws, size_t ws_size,
                              hipStream_t stream) {
    const float* x      = (const float*)d_in[0];
    const float* n1w    = (const float*)d_in[1];
    const float* n1b    = (const float*)d_in[2];
    const float* w_qkv  = (const float*)d_in[3];
    const float* w_dw   = (const float*)d_in[4];
    const float* temp   = (const float*)d_in[5];
    const float* w_proj = (const float*)d_in[6];
    const float* b_proj = (const float*)d_in[7];
    const float* n2w    = (const float*)d_in[8];
    const float* n2b    = (const float*)d_in[9];
    const float* w_in   = (const float*)d_in[10];
    const float* w_dwf  = (const float*)d_in[11];
    const float* w_out  = (const float*)d_in[12];
    float* outp = (float*)d_out;

    // workspace layout: 100,122,624 bytes (unchanged)
    const size_t DCT_B = 147456;
    const size_t CS    = (size_t)Cc * S;
    const size_t X1_B  = (size_t)Bn * CS * 2;
    const size_t P_B   = CS * 2;
    const size_t WB_B  = 884736;
    const size_t NEED  = DCT_B + X1_B + 2 * P_B + (size_t)3 * CS * 2 + WB_B;
    if (ws_size < NEED) return;

    char* p = (char*)d_ws;
    bft* dctb  = (bft*)p;
    bft* dctTb = dctb + L * L;
    p += DCT_B;
    bft* X1    = (bft*)p;                  p += X1_B;
    bft* Pb    = (bft*)p;                  p += P_B;
    bft* Qb    = (bft*)p;                  p += P_B;
    bft* QKV   = (bft*)p;                  p += 3 * CS * 2;
    bft* w_qkv_b = (bft*)p;
    bft* w_proj_b = w_qkv_b + 576 * 192;
    bft* w_in_b  = w_proj_b + 192 * 192;   // 1024x192 remapped
    bft* w_out_b = w_in_b + 1024 * 192;    // 192x512 (pad K)
    bft* fT    = QKV;                      // [12672][1024] = 25.9 MB
    bft* gT    = Qb;                       // [12288][512]  = 12.6 MB
    bft* attnT = QKV + CS;                 // [36864][192]

    k_dct_init<<<144, BLK, 0, stream>>>(dctb, dctTb);
    k_cvt<<<432, BLK, 0, stream>>>(w_qkv, w_qkv_b, 576, 192, 192);
    k_cvt<<<144, BLK, 0, stream>>>(w_proj, w_proj_b, 192, 192, 192);
    k_cvt_ffn<<<768, BLK, 0, stream>>>(w_in, w_in_b);
    k_cvt<<<384, BLK, 0, stream>>>(w_out, w_out_b, 192, 510, 512);

    for (int b = 0; b < Bn; ++b) {
        const float* xb = x + (size_t)b * CS;
        bft* x1b = X1 + (size_t)b * CS;
        // LN1 -> z1 NCHW (Pb)
        k_ln8<float><<<S * 8 / BLK, BLK, 0, stream>>>(xb, n1w, n1b, Pb);
        // G1 (per c): D[h][p] = z1_c . dctb^T -> Tt[p][h] (Qb, OMODE3)
        k_mm<2, 2, 2, 6, 64, 2, 3, false, false, bft, float><<<dim3(1, 3, Cc), 256, 0, stream>>>(
            Pb, L, L, S,  dctb, L, 0,  Qb, L, S,  nullptr, nullptr, 0,  L, 0, 0);
        // G2 (per c): D[p][q] = Tt_c . dctb^T -> yd[c][q*192+p] (Pb, OMODE3)
        k_mm<2, 2, 2, 6, 64, 2, 3, false, false, bft, float><<<dim3(1, 3, Cc), 256, 0, stream>>>(
            Qb, L, L, S,  dctb, L, 0,  Pb, L, S,  nullptr, nullptr, 0,  L, 0, 0);
        // transpose yd -> ydT [s'][c] (Qb)
        k_tr<<<dim3(576, 6), BLK, 0, stream>>>(Pb, Qb);
        // qkv = W_qkv . ydT^T -> QKV [576][S]
        k_mm<2, 2, 4, 4, 64, 2, 0, false, false, bft, float><<<dim3(288, 5, 1), 256, 0, stream>>>(
            w_qkv_b, Cc, 576, 0,  Qb, Cc, 0,  QKV, S, 0,  nullptr, nullptr, 0,  Cc, 0, 0);
        // depthwise 3x3 -> window-tiled: q->Pb, k->Qb, v->QKV[0:CS]
        k_dwconv<<<(Cc * S / 8) / BLK, BLK, 0, stream>>>(QKV, w_dw, Pb);
        k_dwconv<<<(Cc * S / 8) / BLK, BLK, 0, stream>>>(QKV + CS, w_dw + Cc * 9, Qb);
        k_dwconv<<<(Cc * S / 8) / BLK, BLK, 0, stream>>>(QKV + 2 * CS, w_dw + 2 * Cc * 9, QKV);
        // attention -> attnT [s*][c]
        k_attn_mfma<<<dim3(144, 6), 256, 0, stream>>>(Pb, Qb, QKV, temp, attnT);
        // proj + bias; B=attnT rows; window-decode epilogue -> Pb NCHW
        k_mm<2, 2, 4, 4, 64, 2, 2, true, false, bft, float><<<dim3(288, 2, 1), 256, 0, stream>>>(
            w_proj_b, Cc, Cc, 0,  attnT, Cc, 0,  Pb, S, 0,  b_proj, nullptr, 0,  Cc, 0, 0);
        // G3 (per c): D[q][w'] = P_c . dctTb^T -> Ut[w'][q] (Qb, OMODE3)
        k_mm<2, 2, 2, 6, 64, 2, 3, false, false, bft, float><<<dim3(1, 3, Cc), 256, 0, stream>>>(
            Pb, L, L, S,  dctTb, L, 0,  Qb, L, S,  nullptr, nullptr, 0,  L, 0, 0);
        // G4 (per c): D[h'][w'] = dctTb . Ut^T + x -> x1 NCHW
        k_mm<2, 2, 2, 6, 64, 2, 0, false, true, bft, float><<<dim3(1, 3, Cc), 256, 0, stream>>>(
            dctTb, L, L, 0,  Qb, L, S,  x1b, L, S,  nullptr, xb, S,  L, 0, 0);
    }
    for (int b = 0; b < Bn; ++b) {
        bft* x1b = X1 + (size_t)b * CS;
        float* outb = outp + (size_t)b * CS;
        // LN2 -> z^T [s][c] (Pb)
        k_lnT8<bft><<<S * 8 / BLK, BLK, 0, stream>>>(x1b, n2w, n2b, Pb);
        for (int ck = 0; ck < 3; ++ck) {
            int h0 = ck * CH;
            long off = (long)(h0 - 1) * L;       // z^T row offset (incl. top halo)
            int rlo = (h0 == 0) ? L : 0;
            int rhi = (h0 == 2 * CH) ? (FTR - L) : FTR;
            // fT = (W_in . z_chunk)^T : [FTR][1024]
            k_mm<2, 2, 4, 4, 64, 4, 3, false, false, bft, float><<<dim3(99, 8, 1), 256, 0, stream>>>(
                w_in_b, Cc, 1024, 0,  Pb + off * Cc, Cc, 0,  fT, 1024, 0,
                nullptr, nullptr, 0,  Cc, rlo, rhi);
            // gate: fT -> gT [GTR][512]
            k_gateT<<<dim3(GTR / 32, 8), BLK, 0, stream>>>(fT, w_dwf, gT);
            // out = W_out . g + x1 (row-major B, linear out at chunk offset)
            k_mm<2, 2, 2, 4, 64, 2, 0, false, true, float, bft><<<dim3(96, 3, 1), 256, 0, stream>>>(
                w_out_b, 512, 192, 0,  gT, 512, 0,  outb + (size_t)h0 * L, S, 0,
                nullptr, x1b + (size_t)h0 * L, 0,  512, 0, 0);
        }
    }
}

// Round 12
// 779.620 us; speedup vs baseline: 1.3388x; 1.2359x over previous
//
#include <hip/hip_runtime.h>
#include <hip/hip_bf16.h>

typedef __hip_bfloat16 bft;
typedef __attribute__((ext_vector_type(8))) short bf16x8;
typedef __attribute__((ext_vector_type(4))) float f32x4;

#define BLK 256
static constexpr int Cc = 192;     // channels
static constexpr int L  = 192;     // H = W
static constexpr int S  = 36864;   // L*L
static constexpr int Bn = 2;       // batch
static constexpr int HID = 510;    // int(192*2.66)
static constexpr int CH = 64;      // FFN chunk height (image rows)
static constexpr int FTR = (CH + 2) * L;   // 12672 fT rows (with halo)
static constexpr int GTR = CH * L;         // 12288 gT rows
static constexpr double PI_D = 3.141592653589793238462643383279502884;

__device__ __forceinline__ float ldf(const float* p) { return *p; }
__device__ __forceinline__ float ldf(const bft* p)   { return __bfloat162float(*p); }
__device__ __forceinline__ void  stf(float* p, float v) { *p = v; }
__device__ __forceinline__ void  stf(bft* p, float v)   { *p = __float2bfloat16(v); }
__device__ __forceinline__ unsigned short f2bfu(float f) {
    bft h = __float2bfloat16(f);
    return *reinterpret_cast<const unsigned short*>(&h);
}
__device__ __forceinline__ unsigned short bfu(const bft* p) {
    return *reinterpret_cast<const unsigned short*>(p);
}
__device__ __forceinline__ float bu2f(unsigned short u) {
    unsigned int x = (unsigned int)u << 16;
    return __uint_as_float(x);
}
__device__ __forceinline__ bf16x8 ld8(const unsigned short* p) {   // 4B-aligned
    union { unsigned int u[4]; bf16x8 v; } t;
    const unsigned int* q = reinterpret_cast<const unsigned int*>(p);
    t.u[0] = q[0]; t.u[1] = q[1]; t.u[2] = q[2]; t.u[3] = q[3];
    return t.v;
}

// ---------------- DCT matrix init -> bf16 direct + transposed ----------------
__global__ __launch_bounds__(BLK) void k_dct_init(bft* __restrict__ dctb,
                                                  bft* __restrict__ dctTb) {
    int idx = blockIdx.x * BLK + threadIdx.x;
    if (idx >= L * L) return;
    int p = idx / L, h = idx - p * L;
    double v = (p == 0) ? sqrt(1.0 / L)
                        : cos(PI_D * p * (2 * h + 1) / (2.0 * L)) * sqrt(2.0 / L);
    bft bv = __float2bfloat16((float)v);
    dctb[p * L + h] = bv;
    dctTb[h * L + p] = bv;
}

// ---------------- fp32 weight -> bf16 with zero pad --------------------------
__global__ __launch_bounds__(BLK) void k_cvt(const float* __restrict__ src,
                                             bft* __restrict__ dst,
                                             int Mr, int Kr, int Kp) {
    int idx = blockIdx.x * BLK + threadIdx.x;
    int m = idx / Kp, k = idx - m * Kp;
    float v = (m < Mr && k < Kr) ? src[(size_t)m * Kr + k] : 0.f;
    dst[idx] = __float2bfloat16(v);
}

// ---------------- w_in -> bf16, rows remapped: f1 at 0..509, f2 at 512..1021 -
__global__ __launch_bounds__(BLK) void k_cvt_ffn(const float* __restrict__ src,
                                                 bft* __restrict__ dst) {
    int idx = blockIdx.x * BLK + threadIdx.x;   // [0, 1024*192)
    int m = idx / Cc, k = idx - m * Cc;
    float v = 0.f;
    if (m < 510) v = src[(size_t)m * Cc + k];
    else if (m >= 512 && m < 1022) v = src[(size_t)(m - 2) * Cc + k];
    dst[idx] = __float2bfloat16(v);
}

// ---------------- LayerNorm, 8 lanes/pixel, NCHW out (batched via grid.y) ----
template <typename TI>
__global__ __launch_bounds__(BLK) void k_ln8(const TI* __restrict__ x,
                                             const float* __restrict__ w,
                                             const float* __restrict__ b,
                                             bft* __restrict__ out,
                                             long zI, long zO) {
    int t = blockIdx.x * BLK + threadIdx.x;
    int s = t >> 3, u = t & 7;
    const TI* xp = x + (size_t)blockIdx.y * zI + s;
    bft* op = out + (size_t)blockIdx.y * zO;
    float sum = 0.f, sq = 0.f;
#pragma unroll
    for (int j = 0; j < 24; ++j) {
        float v = ldf(xp + (size_t)(u * 24 + j) * S);
        sum += v; sq += v * v;
    }
#pragma unroll
    for (int m = 1; m < 8; m <<= 1) {
        sum += __shfl_xor(sum, m);
        sq  += __shfl_xor(sq, m);
    }
    float mu = sum * (1.f / Cc);
    float var = sq * (1.f / Cc) - mu * mu;
    float r = rsqrtf(var + 1e-5f);
#pragma unroll
    for (int j = 0; j < 24; ++j) {
        int c = u * 24 + j;
        float v = ldf(xp + (size_t)c * S);
        stf(op + (size_t)c * S + s, (v - mu) * r * w[c] + b[c]);
    }
}

// ---------------- LayerNorm, transposed out z^T [s][c] (batched) -------------
template <typename TI>
__global__ __launch_bounds__(BLK) void k_lnT8(const TI* __restrict__ x,
                                              const float* __restrict__ w,
                                              const float* __restrict__ b,
                                              bft* __restrict__ out,
                                              long zI, long zO) {
    int t = blockIdx.x * BLK + threadIdx.x;
    int s = t >> 3, u = t & 7;
    const TI* xp = x + (size_t)blockIdx.y * zI + s;
    float sum = 0.f, sq = 0.f;
#pragma unroll
    for (int j = 0; j < 24; ++j) {
        float v = ldf(xp + (size_t)(u * 24 + j) * S);
        sum += v; sq += v * v;
    }
#pragma unroll
    for (int m = 1; m < 8; m <<= 1) {
        sum += __shfl_xor(sum, m);
        sq  += __shfl_xor(sq, m);
    }
    float mu = sum * (1.f / Cc);
    float var = sq * (1.f / Cc) - mu * mu;
    float r = rsqrtf(var + 1e-5f);
    bft* op = out + (size_t)blockIdx.y * zO + (size_t)s * Cc + u * 24;
#pragma unroll
    for (int q = 0; q < 3; ++q) {
        unsigned short v8[8];
#pragma unroll
        for (int jj = 0; jj < 8; ++jj) {
            int c = u * 24 + q * 8 + jj;
            float v = ldf(xp + (size_t)c * S);
            v8[jj] = f2bfu((v - mu) * r * w[c] + b[c]);
        }
        *reinterpret_cast<uint4*>(op + q * 8) = *reinterpret_cast<uint4*>(v8);
    }
}

// ---------------- transpose [Cc][S] -> [S][Cc] (batched via grid.z) ----------
__global__ __launch_bounds__(BLK) void k_tr(const bft* __restrict__ in,
                                            bft* __restrict__ out, long z) {
    __shared__ unsigned short t[32][72];
    const int tid = threadIdx.x;
    const int s0 = blockIdx.x * 64, c0 = blockIdx.y * 32;
    const bft* ip = in + (size_t)blockIdx.z * z;
    bft* op = out + (size_t)blockIdx.z * z;
    {
        int c = tid >> 3, sc = (tid & 7) * 8;
        *reinterpret_cast<uint4*>(&t[c][sc]) =
            *reinterpret_cast<const uint4*>(ip + (size_t)(c0 + c) * S + s0 + sc);
    }
    __syncthreads();
    {
        int s = tid >> 2, cc = (tid & 3) * 8;
        unsigned short v[8];
#pragma unroll
        for (int q = 0; q < 8; ++q) v[q] = t[cc + q][s];
        *reinterpret_cast<uint4*>(op + (size_t)(s0 + s) * Cc + c0 + cc) =
            *reinterpret_cast<uint4*>(v);
    }
}

// =============================================================================
// Unified MFMA bf16 GEMM. Block = (WR*FM*16) x (WC*FN*16), 4 waves (WR x WC).
//   BMODE: 2 = row-major [n][k]; 4 = row-major with row-range mask [rlo,rhi)
//   OMODE: 0 = linear; 2 = window-tiled -> spatial (+bz*zO); 3 = transposed
// =============================================================================
template <int WR, int WC, int FM, int FN, int KSTEP, int BMODE, int OMODE,
          bool HASBIAS, bool HASRES, typename OutT, typename ResT>
__global__ __launch_bounds__(256) void k_mm(
    const bft* __restrict__ A, int strideA, int Mreal, long zA,
    const bft* __restrict__ B, int strideB, long zB,
    OutT* __restrict__ Out, int strideO, long zO,
    const float* __restrict__ bias,
    const ResT* __restrict__ Res, long zR,
    int K, int rlo, int rhi) {
    constexpr int BM = WR * FM * 16, BN = WC * FN * 16;
    constexpr int AV = KSTEP / 8;
    __shared__ unsigned short Al[BM][KSTEP + 8];
    __shared__ unsigned short Bl[BN][KSTEP + 8];
    const int tid = threadIdx.x;
    const int n0 = blockIdx.x * BN, m0 = blockIdx.y * BM, bz = blockIdx.z;
    const int lane = tid & 63, wv = tid >> 6;
    const int wr = wv / WC, wc = wv % WC;
    const int l15 = lane & 15, l4 = lane >> 4;
    f32x4 acc[FM][FN] = {};

    const bft* Ab = A + (size_t)bz * zA;
    const bft* Bb = B + (size_t)bz * zB;

    for (int k0 = 0; k0 < K; k0 += KSTEP) {
        for (int id = tid; id < BM * AV; id += 256) {
            int row = id / AV, kc = (id % AV) * 8;
            int gm = m0 + row; if (gm >= Mreal) gm = Mreal - 1;
            *reinterpret_cast<uint4*>(&Al[row][kc]) =
                *reinterpret_cast<const uint4*>(Ab + (size_t)gm * strideA + k0 + kc);
        }
        for (int id = tid; id < BN * AV; id += 256) {
            int row = id / AV, kc = (id % AV) * 8;
            int gn = n0 + row;
            uint4 val;
            if constexpr (BMODE == 2) {
                val = *reinterpret_cast<const uint4*>(
                    Bb + (size_t)gn * strideB + k0 + kc);
            } else {  // BMODE 4: masked row range
                if (gn >= rlo && gn < rhi)
                    val = *reinterpret_cast<const uint4*>(
                        Bb + (size_t)gn * strideB + k0 + kc);
                else
                    val = make_uint4(0, 0, 0, 0);
            }
            *reinterpret_cast<uint4*>(&Bl[row][kc]) = val;
        }
        __syncthreads();
#pragma unroll
        for (int kk = 0; kk < KSTEP / 32; ++kk) {
            bf16x8 af[FM], bf[FN];
#pragma unroll
            for (int i = 0; i < FM; ++i)
                af[i] = *reinterpret_cast<const bf16x8*>(
                    &Al[wr * FM * 16 + i * 16 + l15][kk * 32 + l4 * 8]);
#pragma unroll
            for (int j = 0; j < FN; ++j)
                bf[j] = *reinterpret_cast<const bf16x8*>(
                    &Bl[wc * FN * 16 + j * 16 + l15][kk * 32 + l4 * 8]);
#pragma unroll
            for (int i = 0; i < FM; ++i)
#pragma unroll
                for (int j = 0; j < FN; ++j)
                    acc[i][j] = __builtin_amdgcn_mfma_f32_16x16x32_bf16(
                        af[i], bf[j], acc[i][j], 0, 0, 0);
        }
        __syncthreads();
    }
    if constexpr (OMODE == 3) {
#pragma unroll
        for (int i = 0; i < FM; ++i) {
            int mB = m0 + wr * FM * 16 + i * 16 + l4 * 4;
#pragma unroll
            for (int j = 0; j < FN; ++j) {
                int n = n0 + wc * FN * 16 + j * 16 + l15;
                unsigned short v[4];
#pragma unroll
                for (int r = 0; r < 4; ++r) v[r] = f2bfu(acc[i][j][r]);
                *reinterpret_cast<uint2*>((bft*)Out + (size_t)bz * zO
                    + (size_t)n * strideO + mB) = *reinterpret_cast<uint2*>(v);
            }
        }
        return;
    }
#pragma unroll
    for (int i = 0; i < FM; ++i) {
        int mB = m0 + wr * FM * 16 + i * 16 + l4 * 4;
#pragma unroll
        for (int j = 0; j < FN; ++j) {
            int n = n0 + wc * FN * 16 + j * 16 + l15;
#pragma unroll
            for (int r = 0; r < 4; ++r) {
                int m = mB + r;
                if (m >= Mreal) continue;
                float vv = acc[i][j][r];
                if constexpr (HASBIAS) vv += bias[m];
                size_t idx;
                if constexpr (OMODE == 0)
                    idx = (size_t)bz * zO + (size_t)m * strideO + n;
                else {
                    int win = n >> 6, e = n & 63;
                    int hh = ((win / 24) << 3) + (e >> 3);
                    int ww = ((win % 24) << 3) + (e & 7);
                    idx = (size_t)bz * zO + (size_t)m * S + (size_t)hh * L + ww;
                }
                if constexpr (HASRES) vv += ldf(Res + ((OMODE == 0)
                                  ? ((size_t)bz * zR + (size_t)m * strideO + n) : idx));
                stf(Out + idx, vv);
            }
        }
    }
}

// ---------------- depthwise 3x3 (batched) -> window-tiled --------------------
__global__ __launch_bounds__(BLK) void k_dwconv(const bft* __restrict__ in,
                                                long inZ,
                                                const float* __restrict__ wt,
                                                bft* __restrict__ out,
                                                long outZ) {
    int t = blockIdx.x * BLK + threadIdx.x;      // [0, Bn*Cc*S/8)
    int ch2 = t / (S / 8);
    int rem = t - ch2 * (S / 8);
    int b = ch2 / Cc, ch = ch2 - b * Cc;
    int h = rem / 24, wb = (rem - h * 24) * 8;
    const float* wp = wt + (size_t)ch * 9;
    const bft* ip = in + (size_t)b * inZ + (size_t)ch * S;
    float acc[8] = {};
#pragma unroll
    for (int dy = -1; dy <= 1; ++dy) {
        int hh = h + dy;
        if (hh < 0 || hh >= L) continue;
        const bft* rp = ip + hh * L + wb;
        float e[10];
        uint4 mid = *reinterpret_cast<const uint4*>(rp);
        const unsigned short* ms = reinterpret_cast<const unsigned short*>(&mid);
#pragma unroll
        for (int q = 0; q < 8; ++q) e[q + 1] = bu2f(ms[q]);
        e[0] = (wb > 0) ? ldf(rp - 1) : 0.f;
        e[9] = (wb + 8 < L) ? ldf(rp + 8) : 0.f;
        float c0 = wp[(dy + 1) * 3], c1 = wp[(dy + 1) * 3 + 1], c2 = wp[(dy + 1) * 3 + 2];
#pragma unroll
        for (int q = 0; q < 8; ++q)
            acc[q] += c0 * e[q] + c1 * e[q + 1] + c2 * e[q + 2];
    }
    int win = (h >> 3) * 24 + (wb >> 3);
    int e0 = (h & 7) * 8;
    unsigned short ov[8];
#pragma unroll
    for (int q = 0; q < 8; ++q) ov[q] = f2bfu(acc[q]);
    *reinterpret_cast<uint4*>(out + (size_t)b * outZ + (size_t)ch * S + win * 64 + e0) =
        *reinterpret_cast<uint4*>(ov);
}

// ---------------- window channel attention via MFMA; out = [s*][Cc] ----------
__global__ __launch_bounds__(256) void k_attn_mfma(
    const bft* __restrict__ QW, long zQ,
    const bft* __restrict__ KW, long zK,
    const bft* __restrict__ VW, long zV,
    const float* __restrict__ temp,
    bft* __restrict__ outp, long zO) {
    __shared__ unsigned short qls[4][32 * 66];
    __shared__ unsigned short kls[4][32 * 66];
    __shared__ unsigned short vls[4][32 * 66];
    __shared__ float rqs[4][32], rks[4][32];
    const int tid = threadIdx.x;
    const int wv = tid >> 6, lane = tid & 63;
    const int win = blockIdx.x * 4 + wv;
    const int hd = blockIdx.y;
    const int bz = blockIdx.z;
    const int l15 = lane & 15, l4 = lane >> 4;
    unsigned short* ql = qls[wv];
    unsigned short* kl = kls[wv];
    unsigned short* vl = vls[wv];
    const size_t base = (size_t)(hd * 32) * S + (size_t)win * 64;

#pragma unroll
    for (int i = 0; i < 4; ++i) {
        int c = i * 8 + (lane >> 3), e0 = (lane & 7) * 8;
        size_t g = base + (size_t)c * S + e0;
        uint4 vq = *reinterpret_cast<const uint4*>(QW + (size_t)bz * zQ + g);
        uint4 vk = *reinterpret_cast<const uint4*>(KW + (size_t)bz * zK + g);
        uint4 vvv = *reinterpret_cast<const uint4*>(VW + (size_t)bz * zV + g);
        unsigned int* dq = reinterpret_cast<unsigned int*>(&ql[c * 66 + e0]);
        unsigned int* dk = reinterpret_cast<unsigned int*>(&kl[c * 66 + e0]);
        unsigned int* dv = reinterpret_cast<unsigned int*>(&vl[c * 66 + e0]);
        dq[0] = vq.x; dq[1] = vq.y; dq[2] = vq.z; dq[3] = vq.w;
        dk[0] = vk.x; dk[1] = vk.y; dk[2] = vk.z; dk[3] = vk.w;
        dv[0] = vvv.x; dv[1] = vvv.y; dv[2] = vvv.z; dv[3] = vvv.w;
    }
    __syncthreads();
    {
        int row = lane & 31;
        const unsigned short* src = (lane < 32) ? ql : kl;
        float s = 0.f;
#pragma unroll
        for (int w = 0; w < 32; ++w) {
            unsigned int d = *reinterpret_cast<const unsigned int*>(&src[row * 66 + 2 * w]);
            float a = bu2f((unsigned short)(d & 0xffff));
            float b = bu2f((unsigned short)(d >> 16));
            s += a * a + b * b;
        }
        float r = 1.f / fmaxf(sqrtf(s), 1e-12f);
        if (lane < 32) rqs[wv][row] = r; else rks[wv][row] = r;
    }
    __syncthreads();
    f32x4 at[2][2] = {};
#pragma unroll
    for (int ks = 0; ks < 2; ++ks) {
        bf16x8 aq[2], bk[2];
#pragma unroll
        for (int i = 0; i < 2; ++i)
            aq[i] = ld8(&ql[(i * 16 + l15) * 66 + ks * 32 + l4 * 8]);
#pragma unroll
        for (int j = 0; j < 2; ++j)
            bk[j] = ld8(&kl[(j * 16 + l15) * 66 + ks * 32 + l4 * 8]);
#pragma unroll
        for (int i = 0; i < 2; ++i)
#pragma unroll
            for (int j = 0; j < 2; ++j)
                at[i][j] = __builtin_amdgcn_mfma_f32_16x16x32_bf16(
                    aq[i], bk[j], at[i][j], 0, 0, 0);
    }
    float tpr = temp[hd];
    float rk0 = rks[wv][l15] * tpr, rk1 = rks[wv][16 + l15] * tpr;
    float pr[2][2][4];
#pragma unroll
    for (int i = 0; i < 2; ++i)
#pragma unroll
        for (int r = 0; r < 4; ++r) {
            int c = i * 16 + l4 * 4 + r;
            float rq = rqs[wv][c];
            float v0 = at[i][0][r] * rq * rk0;
            float v1 = at[i][1][r] * rq * rk1;
            float mx = fmaxf(v0, v1);
#pragma unroll
            for (int m = 1; m < 16; m <<= 1) mx = fmaxf(mx, __shfl_xor(mx, m));
            v0 = __expf(v0 - mx);
            v1 = __expf(v1 - mx);
            float sm = v0 + v1;
#pragma unroll
            for (int m = 1; m < 16; m <<= 1) sm += __shfl_xor(sm, m);
            float inv = 1.f / sm;
            pr[i][0][r] = v0 * inv;
            pr[i][1][r] = v1 * inv;
        }
    __syncthreads();
    unsigned short* pl = ql;
#pragma unroll
    for (int i = 0; i < 2; ++i)
#pragma unroll
        for (int j = 0; j < 2; ++j)
#pragma unroll
            for (int r = 0; r < 4; ++r)
                pl[(i * 16 + l4 * 4 + r) * 34 + j * 16 + l15] = f2bfu(pr[i][j][r]);
    __syncthreads();
    bf16x8 ap[2];
#pragma unroll
    for (int i = 0; i < 2; ++i)
        ap[i] = ld8(&pl[(i * 16 + l15) * 34 + l4 * 8]);
    f32x4 o[2][4] = {};
#pragma unroll
    for (int j = 0; j < 4; ++j) {
        unsigned short tv[8];
#pragma unroll
        for (int q = 0; q < 8; ++q)
            tv[q] = vl[(l4 * 8 + q) * 66 + j * 16 + l15];
        bf16x8 bv = *reinterpret_cast<bf16x8*>(tv);
#pragma unroll
        for (int i = 0; i < 2; ++i)
            o[i][j] = __builtin_amdgcn_mfma_f32_16x16x32_bf16(ap[i], bv, o[i][j], 0, 0, 0);
    }
#pragma unroll
    for (int i = 0; i < 2; ++i)
#pragma unroll
        for (int j = 0; j < 4; ++j) {
            int e = j * 16 + l15, cl = i * 16 + l4 * 4;
            unsigned short v[4];
#pragma unroll
            for (int r = 0; r < 4; ++r) v[r] = f2bfu(o[i][j][r]);
            unsigned short* row = ((e < 32) ? kl : vl) + (e & 31) * 40 + cl;
            *reinterpret_cast<uint2*>(row) = *reinterpret_cast<uint2*>(v);
        }
    {
        const unsigned short* row = ((lane < 32) ? kl : vl) + (lane & 31) * 40;
        bft* dst = outp + (size_t)bz * zO + (size_t)(win * 64 + lane) * Cc + hd * 32;
#pragma unroll
        for (int q = 0; q < 4; ++q)
            *reinterpret_cast<uint4*>(dst + q * 8) =
                *reinterpret_cast<const uint4*>(row + q * 8);
    }
}

// ---------------- FFN gate (transposed, batched): fT -> gT -------------------
__global__ __launch_bounds__(BLK) void k_gateT(const bft* __restrict__ fTg,
                                               const float* __restrict__ wt,
                                               bft* __restrict__ gTg) {
    __shared__ float w1s[64][9];
    __shared__ float w2s[64][9];
    const int tid = threadIdx.x;
    const int cbase = blockIdx.y * 64;
    const bft* fT = fTg + (size_t)blockIdx.z * FTR * 1024;
    bft* gT = gTg + (size_t)blockIdx.z * GTR * 512;
    for (int id = tid; id < 576; id += BLK) {
        int cl = id / 9, k = id - cl * 9;
        int c = cbase + cl;
        w1s[cl][k] = (c < HID) ? wt[(size_t)c * 9 + k] : 0.f;
        w2s[cl][k] = (c < HID) ? wt[(size_t)(c + HID) * 9 + k] : 0.f;
    }
    __syncthreads();
    int px = blockIdx.x * 32 + (tid >> 3);
    int cgl = (tid & 7) * 8;
    int hc = px / L, w = px - hc * L;
    float a1[8] = {}, a2[8] = {};
#pragma unroll
    for (int dy = 0; dy < 3; ++dy) {
#pragma unroll
        for (int dx = 0; dx < 3; ++dx) {
            int ww = w + dx - 1;
            if (ww < 0 || ww >= L) continue;
            size_t frow = (size_t)((hc + dy) * L + ww) * 1024 + cbase + cgl;
            uint4 u1 = *reinterpret_cast<const uint4*>(fT + frow);
            uint4 u2 = *reinterpret_cast<const uint4*>(fT + frow + 512);
            const unsigned short* e1 = reinterpret_cast<const unsigned short*>(&u1);
            const unsigned short* e2 = reinterpret_cast<const unsigned short*>(&u2);
            int k = dy * 3 + dx;
#pragma unroll
            for (int j = 0; j < 8; ++j) {
                a1[j] += w1s[cgl + j][k] * bu2f(e1[j]);
                a2[j] += w2s[cgl + j][k] * bu2f(e2[j]);
            }
        }
    }
    unsigned short ov[8];
#pragma unroll
    for (int j = 0; j < 8; ++j) {
        float ge = 0.5f * a1[j] * (1.f + erff(a1[j] * 0.70710678118654752f));
        ov[j] = f2bfu(ge * a2[j]);
    }
    *reinterpret_cast<uint4*>(gT + (size_t)px * 512 + cbase + cgl) =
        *reinterpret_cast<uint4*>(ov);
}

// -----------------------------------------------------------------------------
extern "C" void kernel_launch(void* const* d_in, const int* in_sizes, int n_in,
                              void* d_out, int out_size, void* d_ws, size_t ws_size,
                              hipStream_t stream) {
    const float* x      = (const float*)d_in[0];
    const float* n1w    = (const float*)d_in[1];
    const float* n1b    = (const float*)d_in[2];
    const float* w_qkv  = (const float*)d_in[3];
    const float* w_dw   = (const float*)d_in[4];
    const float* temp   = (const float*)d_in[5];
    const float* w_proj = (const float*)d_in[6];
    const float* b_proj = (const float*)d_in[7];
    const float* n2w    = (const float*)d_in[8];
    const float* n2b    = (const float*)d_in[9];
    const float* w_in   = (const float*)d_in[10];
    const float* w_dwf  = (const float*)d_in[11];
    const float* w_out  = (const float*)d_in[12];
    float* outp = (float*)d_out;

    // workspace: 170,901,504 bytes (2-batch buffers; ws ≈ 256 MiB per profile)
    const long CS = (long)Cc * S;                     // elements per batch-plane
    const size_t DCT_B = 147456;
    const size_t BUF_B = (size_t)Bn * CS * 2;         // 28,311,552
    const size_t QKV_B = (size_t)Bn * 3 * CS * 2;     // 84,934,656
    const size_t WB_B  = 884736;
    const size_t NEED  = DCT_B + 3 * BUF_B + QKV_B + WB_B;
    if (ws_size < NEED) return;                        // clean fail if ws smaller

    char* p = (char*)d_ws;
    bft* dctb  = (bft*)p;
    bft* dctTb = dctb + L * L;
    p += DCT_B;
    bft* X1    = (bft*)p;                  p += BUF_B;   // [2][Cc][S]
    bft* PbB   = (bft*)p;                  p += BUF_B;   // [2][Cc][S]
    bft* QbB   = (bft*)p;                  p += BUF_B;   // [2][Cc][S]
    bft* QKV   = (bft*)p;                  p += QKV_B;   // [2][576][S]
    bft* w_qkv_b = (bft*)p;
    bft* w_proj_b = w_qkv_b + 576 * 192;
    bft* w_in_b  = w_proj_b + 192 * 192;   // 1024x192 remapped
    bft* w_out_b = w_in_b + 1024 * 192;    // 192x512 (pad K)
    bft* fT = QKV;                         // [2][FTR][1024] = 51.9 MB
    bft* gT = QKV + (size_t)Bn * FTR * 1024;  // [2][GTR][512] = 25.2 MB
    bft* attnT = QKV + CS;                 // per-b at QKV + b*3CS + CS

    k_dct_init<<<144, BLK, 0, stream>>>(dctb, dctTb);
    k_cvt<<<432, BLK, 0, stream>>>(w_qkv, w_qkv_b, 576, 192, 192);
    k_cvt<<<144, BLK, 0, stream>>>(w_proj, w_proj_b, 192, 192, 192);
    k_cvt_ffn<<<768, BLK, 0, stream>>>(w_in, w_in_b);
    k_cvt<<<384, BLK, 0, stream>>>(w_out, w_out_b, 192, 510, 512);

    // ---------------- attention branch (both batches per dispatch) -----------
    // LN1 -> z1 NCHW (PbB)
    k_ln8<float><<<dim3(S * 8 / BLK, Bn), BLK, 0, stream>>>(x, n1w, n1b, PbB, CS, CS);
    // G1 (per b,c): Tt = (z1_c . dctb^T)^T -> QbB
    k_mm<2, 2, 2, 6, 64, 2, 3, false, false, bft, float><<<dim3(1, 3, Bn * Cc), 256, 0, stream>>>(
        PbB, L, L, S,  dctb, L, 0,  QbB, L, S,  nullptr, nullptr, 0,  L, 0, 0);
    // G2 (per b,c): yd = (Tt_c . dctb^T)^T -> PbB
    k_mm<2, 2, 2, 6, 64, 2, 3, false, false, bft, float><<<dim3(1, 3, Bn * Cc), 256, 0, stream>>>(
        QbB, L, L, S,  dctb, L, 0,  PbB, L, S,  nullptr, nullptr, 0,  L, 0, 0);
    // transpose yd -> ydT [s'][c] (QbB)
    k_tr<<<dim3(576, 6, Bn), BLK, 0, stream>>>(PbB, QbB, CS);
    // qkv = W_qkv . ydT^T -> QKV [b][576][S]
    k_mm<2, 2, 4, 4, 64, 2, 0, false, false, bft, float><<<dim3(288, 5, Bn), 256, 0, stream>>>(
        w_qkv_b, Cc, 576, 0,  QbB, Cc, CS,  QKV, S, 3 * CS,  nullptr, nullptr, 0,  Cc, 0, 0);
    // depthwise 3x3 -> window-tiled: q->PbB, k->QbB, v->QKV[b][0:192]
    k_dwconv<<<6912, BLK, 0, stream>>>(QKV, 3 * CS, w_dw, PbB, CS);
    k_dwconv<<<6912, BLK, 0, stream>>>(QKV + CS, 3 * CS, w_dw + Cc * 9, QbB, CS);
    k_dwconv<<<6912, BLK, 0, stream>>>(QKV + 2 * CS, 3 * CS, w_dw + 2 * Cc * 9, QKV, 3 * CS);
    // attention -> attnT [b][s*][c] at QKV + b*3CS + CS
    k_attn_mfma<<<dim3(144, 6, Bn), 256, 0, stream>>>(
        PbB, CS, QbB, CS, QKV, 3 * CS, temp, attnT, 3 * CS);
    // proj + bias; window-decode -> QbB NCHW
    k_mm<2, 2, 4, 4, 64, 2, 2, true, false, bft, float><<<dim3(288, 2, Bn), 256, 0, stream>>>(
        w_proj_b, Cc, Cc, 0,  attnT, Cc, 3 * CS,  QbB, S, CS,  b_proj, nullptr, 0,  Cc, 0, 0);
    // G3 (per b,c): Ut = (P_c . dctTb^T)^T -> PbB
    k_mm<2, 2, 2, 6, 64, 2, 3, false, false, bft, float><<<dim3(1, 3, Bn * Cc), 256, 0, stream>>>(
        QbB, L, L, S,  dctTb, L, 0,  PbB, L, S,  nullptr, nullptr, 0,  L, 0, 0);
    // G4 (per b,c): x1 = dctTb . Ut^T + x -> X1 NCHW
    k_mm<2, 2, 2, 6, 64, 2, 0, false, true, bft, float><<<dim3(1, 3, Bn * Cc), 256, 0, stream>>>(
        dctTb, L, L, 0,  PbB, L, S,  X1, L, S,  nullptr, x, S,  L, 0, 0);

    // ---------------- FFN branch (both batches per dispatch) -----------------
    // LN2 -> z^T [b][s][c] (QbB)
    k_lnT8<bft><<<dim3(S * 8 / BLK, Bn), BLK, 0, stream>>>(X1, n2w, n2b, QbB, CS, CS);
    for (int ck = 0; ck < 3; ++ck) {
        int h0 = ck * CH;
        long off = (long)(h0 - 1) * L;           // z^T row offset (incl. top halo)
        int rlo = (h0 == 0) ? L : 0;
        int rhi = (h0 == 2 * CH) ? (FTR - L) : FTR;
        // fT = (W_in . z_chunk)^T : [b][FTR][1024]
        k_mm<2, 2, 4, 4, 64, 4, 3, false, false, bft, float><<<dim3(99, 8, Bn), 256, 0, stream>>>(
            w_in_b, Cc, 1024, 0,  QbB + off * Cc, Cc, CS,  fT, 1024, (long)FTR * 1024,
            nullptr, nullptr, 0,  Cc, rlo, rhi);
        // gate: fT -> gT [b][GTR][512]
        k_gateT<<<dim3(GTR / 32, 8, Bn), BLK, 0, stream>>>(fT, w_dwf, gT);
        // out = W_out . g + x1 (row-major B, linear out at chunk offset)
        k_mm<2, 2, 2, 4, 64, 2, 0, false, true, float, bft><<<dim3(96, 3, Bn), 256, 0, stream>>>(
            w_out_b, 512, 192, 0,  gT, 512, (long)GTR * 512,
            outp + (size_t)h0 * L, S, CS,
            nullptr, X1 + (size_t)h0 * L, CS,  512, 0, 0);
    }
}

// Round 13
// 768.192 us; speedup vs baseline: 1.3587x; 1.0149x over previous
//
#include <hip/hip_runtime.h>
#include <hip/hip_bf16.h>

typedef __hip_bfloat16 bft;
typedef __attribute__((ext_vector_type(8))) short bf16x8;
typedef __attribute__((ext_vector_type(4))) float f32x4;

#define BLK 256
static constexpr int Cc = 192;     // channels
static constexpr int L  = 192;     // H = W
static constexpr int S  = 36864;   // L*L
static constexpr int Bn = 2;       // batch
static constexpr int HID = 510;    // int(192*2.66)
static constexpr int CH = 64;      // FFN chunk height (image rows)
static constexpr int FTR = (CH + 2) * L;   // 12672 fT rows (with halo)
static constexpr int GTR = CH * L;         // 12288 gT rows
static constexpr double PI_D = 3.141592653589793238462643383279502884;

__device__ __forceinline__ float ldf(const float* p) { return *p; }
__device__ __forceinline__ float ldf(const bft* p)   { return __bfloat162float(*p); }
__device__ __forceinline__ void  stf(float* p, float v) { *p = v; }
__device__ __forceinline__ void  stf(bft* p, float v)   { *p = __float2bfloat16(v); }
__device__ __forceinline__ unsigned short f2bfu(float f) {
    bft h = __float2bfloat16(f);
    return *reinterpret_cast<const unsigned short*>(&h);
}
__device__ __forceinline__ unsigned short bfu(const bft* p) {
    return *reinterpret_cast<const unsigned short*>(p);
}
__device__ __forceinline__ float bu2f(unsigned short u) {
    unsigned int x = (unsigned int)u << 16;
    return __uint_as_float(x);
}
__device__ __forceinline__ bf16x8 ld8(const unsigned short* p) {   // 4B-aligned
    union { unsigned int u[4]; bf16x8 v; } t;
    const unsigned int* q = reinterpret_cast<const unsigned int*>(p);
    t.u[0] = q[0]; t.u[1] = q[1]; t.u[2] = q[2]; t.u[3] = q[3];
    return t.v;
}

// ---------------- DCT matrix init -> bf16 direct + transposed ----------------
__global__ __launch_bounds__(BLK) void k_dct_init(bft* __restrict__ dctb,
                                                  bft* __restrict__ dctTb) {
    int idx = blockIdx.x * BLK + threadIdx.x;
    if (idx >= L * L) return;
    int p = idx / L, h = idx - p * L;
    double v = (p == 0) ? sqrt(1.0 / L)
                        : cos(PI_D * p * (2 * h + 1) / (2.0 * L)) * sqrt(2.0 / L);
    bft bv = __float2bfloat16((float)v);
    dctb[p * L + h] = bv;
    dctTb[h * L + p] = bv;
}

// ---------------- fp32 weight -> bf16 with zero pad --------------------------
__global__ __launch_bounds__(BLK) void k_cvt(const float* __restrict__ src,
                                             bft* __restrict__ dst,
                                             int Mr, int Kr, int Kp) {
    int idx = blockIdx.x * BLK + threadIdx.x;
    int m = idx / Kp, k = idx - m * Kp;
    float v = (m < Mr && k < Kr) ? src[(size_t)m * Kr + k] : 0.f;
    dst[idx] = __float2bfloat16(v);
}

// ---------------- w_in -> bf16, rows remapped: f1 at 0..509, f2 at 512..1021 -
__global__ __launch_bounds__(BLK) void k_cvt_ffn(const float* __restrict__ src,
                                                 bft* __restrict__ dst) {
    int idx = blockIdx.x * BLK + threadIdx.x;   // [0, 1024*192)
    int m = idx / Cc, k = idx - m * Cc;
    float v = 0.f;
    if (m < 510) v = src[(size_t)m * Cc + k];
    else if (m >= 512 && m < 1022) v = src[(size_t)(m - 2) * Cc + k];
    dst[idx] = __float2bfloat16(v);
}

// ---------------- LayerNorm, 8 lanes/pixel, NCHW out (single-read, batched) --
template <typename TI>
__global__ __launch_bounds__(BLK) void k_ln8(const TI* __restrict__ x,
                                             const float* __restrict__ w,
                                             const float* __restrict__ b,
                                             bft* __restrict__ out,
                                             long zI, long zO) {
    int t = blockIdx.x * BLK + threadIdx.x;
    int s = t >> 3, u = t & 7;
    const TI* xp = x + (size_t)blockIdx.y * zI + s;
    bft* op = out + (size_t)blockIdx.y * zO;
    float vals[24];
    float sum = 0.f, sq = 0.f;
#pragma unroll
    for (int j = 0; j < 24; ++j) {
        vals[j] = ldf(xp + (size_t)(u * 24 + j) * S);
        sum += vals[j]; sq += vals[j] * vals[j];
    }
#pragma unroll
    for (int m = 1; m < 8; m <<= 1) {
        sum += __shfl_xor(sum, m);
        sq  += __shfl_xor(sq, m);
    }
    float mu = sum * (1.f / Cc);
    float var = sq * (1.f / Cc) - mu * mu;
    float r = rsqrtf(var + 1e-5f);
#pragma unroll
    for (int j = 0; j < 24; ++j) {
        int c = u * 24 + j;
        stf(op + (size_t)c * S + s, (vals[j] - mu) * r * w[c] + b[c]);
    }
}

// ---------------- LayerNorm, transposed out z^T [s][c] (single-read) ---------
template <typename TI>
__global__ __launch_bounds__(BLK) void k_lnT8(const TI* __restrict__ x,
                                              const float* __restrict__ w,
                                              const float* __restrict__ b,
                                              bft* __restrict__ out,
                                              long zI, long zO) {
    int t = blockIdx.x * BLK + threadIdx.x;
    int s = t >> 3, u = t & 7;
    const TI* xp = x + (size_t)blockIdx.y * zI + s;
    float vals[24];
    float sum = 0.f, sq = 0.f;
#pragma unroll
    for (int j = 0; j < 24; ++j) {
        vals[j] = ldf(xp + (size_t)(u * 24 + j) * S);
        sum += vals[j]; sq += vals[j] * vals[j];
    }
#pragma unroll
    for (int m = 1; m < 8; m <<= 1) {
        sum += __shfl_xor(sum, m);
        sq  += __shfl_xor(sq, m);
    }
    float mu = sum * (1.f / Cc);
    float var = sq * (1.f / Cc) - mu * mu;
    float r = rsqrtf(var + 1e-5f);
    bft* op = out + (size_t)blockIdx.y * zO + (size_t)s * Cc + u * 24;
#pragma unroll
    for (int q = 0; q < 3; ++q) {
        unsigned short v8[8];
#pragma unroll
        for (int jj = 0; jj < 8; ++jj) {
            int c = u * 24 + q * 8 + jj;
            v8[jj] = f2bfu((vals[q * 8 + jj] - mu) * r * w[c] + b[c]);
        }
        *reinterpret_cast<uint4*>(op + q * 8) = *reinterpret_cast<uint4*>(v8);
    }
}

// ---------------- transpose [Cc][S] -> [S][Cc] (batched via grid.z) ----------
__global__ __launch_bounds__(BLK) void k_tr(const bft* __restrict__ in,
                                            bft* __restrict__ out, long z) {
    __shared__ unsigned short t[32][72];
    const int tid = threadIdx.x;
    const int s0 = blockIdx.x * 64, c0 = blockIdx.y * 32;
    const bft* ip = in + (size_t)blockIdx.z * z;
    bft* op = out + (size_t)blockIdx.z * z;
    {
        int c = tid >> 3, sc = (tid & 7) * 8;
        *reinterpret_cast<uint4*>(&t[c][sc]) =
            *reinterpret_cast<const uint4*>(ip + (size_t)(c0 + c) * S + s0 + sc);
    }
    __syncthreads();
    {
        int s = tid >> 2, cc = (tid & 3) * 8;
        unsigned short v[8];
#pragma unroll
        for (int q = 0; q < 8; ++q) v[q] = t[cc + q][s];
        *reinterpret_cast<uint4*>(op + (size_t)(s0 + s) * Cc + c0 + cc) =
            *reinterpret_cast<uint4*>(v);
    }
}

// =============================================================================
// Unified MFMA bf16 GEMM. Block = (WR*FM*16) x (WC*FN*16), 4 waves (WR x WC).
//   BMODE: 2 = row-major [n][k]; 4 = row-major with row-range mask [rlo,rhi)
//   OMODE: 0 = linear; 2 = window-tiled -> spatial (+bz*zO);
//          3 = transposed, LDS-restaged coalesced full-row writes
// =============================================================================
template <int WR, int WC, int FM, int FN, int KSTEP, int BMODE, int OMODE,
          bool HASBIAS, bool HASRES, typename OutT, typename ResT>
__global__ __launch_bounds__(256) void k_mm(
    const bft* __restrict__ A, int strideA, int Mreal, long zA,
    const bft* __restrict__ B, int strideB, long zB,
    OutT* __restrict__ Out, int strideO, long zO,
    const float* __restrict__ bias,
    const ResT* __restrict__ Res, long zR,
    int K, int rlo, int rhi) {
    constexpr int BM = WR * FM * 16, BN = WC * FN * 16;
    constexpr int AV = KSTEP / 8;
    __shared__ unsigned short lds[(BM + BN) * (KSTEP + 8)];
    unsigned short (*Al)[KSTEP + 8] =
        reinterpret_cast<unsigned short(*)[KSTEP + 8]>(lds);
    unsigned short (*Bl)[KSTEP + 8] =
        reinterpret_cast<unsigned short(*)[KSTEP + 8]>(lds + BM * (KSTEP + 8));
    const int tid = threadIdx.x;
    const int n0 = blockIdx.x * BN, m0 = blockIdx.y * BM, bz = blockIdx.z;
    const int lane = tid & 63, wv = tid >> 6;
    const int wr = wv / WC, wc = wv % WC;
    const int l15 = lane & 15, l4 = lane >> 4;
    f32x4 acc[FM][FN] = {};

    const bft* Ab = A + (size_t)bz * zA;
    const bft* Bb = B + (size_t)bz * zB;

    for (int k0 = 0; k0 < K; k0 += KSTEP) {
        for (int id = tid; id < BM * AV; id += 256) {
            int row = id / AV, kc = (id % AV) * 8;
            int gm = m0 + row; if (gm >= Mreal) gm = Mreal - 1;
            *reinterpret_cast<uint4*>(&Al[row][kc]) =
                *reinterpret_cast<const uint4*>(Ab + (size_t)gm * strideA + k0 + kc);
        }
        for (int id = tid; id < BN * AV; id += 256) {
            int row = id / AV, kc = (id % AV) * 8;
            int gn = n0 + row;
            uint4 val;
            if constexpr (BMODE == 2) {
                val = *reinterpret_cast<const uint4*>(
                    Bb + (size_t)gn * strideB + k0 + kc);
            } else {  // BMODE 4: masked row range
                if (gn >= rlo && gn < rhi)
                    val = *reinterpret_cast<const uint4*>(
                        Bb + (size_t)gn * strideB + k0 + kc);
                else
                    val = make_uint4(0, 0, 0, 0);
            }
            *reinterpret_cast<uint4*>(&Bl[row][kc]) = val;
        }
        __syncthreads();
#pragma unroll
        for (int kk = 0; kk < KSTEP / 32; ++kk) {
            bf16x8 af[FM], bf[FN];
#pragma unroll
            for (int i = 0; i < FM; ++i)
                af[i] = *reinterpret_cast<const bf16x8*>(
                    &Al[wr * FM * 16 + i * 16 + l15][kk * 32 + l4 * 8]);
#pragma unroll
            for (int j = 0; j < FN; ++j)
                bf[j] = *reinterpret_cast<const bf16x8*>(
                    &Bl[wc * FN * 16 + j * 16 + l15][kk * 32 + l4 * 8]);
#pragma unroll
            for (int i = 0; i < FM; ++i)
#pragma unroll
                for (int j = 0; j < FN; ++j)
                    acc[i][j] = __builtin_amdgcn_mfma_f32_16x16x32_bf16(
                        af[i], bf[j], acc[i][j], 0, 0, 0);
        }
        __syncthreads();
    }
    if constexpr (OMODE == 3) {
        // restage [BN][BM] tile in LDS (row stride BM+8 shorts, 16B-aligned),
        // then stream full 128B row segments to global (no partial-line RMW).
        constexpr int OST = BM + 8;
        unsigned short* Ol = lds;
#pragma unroll
        for (int i = 0; i < FM; ++i) {
            int mB = wr * FM * 16 + i * 16 + l4 * 4;
#pragma unroll
            for (int j = 0; j < FN; ++j) {
                int n = wc * FN * 16 + j * 16 + l15;
                unsigned short v[4];
#pragma unroll
                for (int r = 0; r < 4; ++r) v[r] = f2bfu(acc[i][j][r]);
                *reinterpret_cast<uint2*>(&Ol[n * OST + mB]) =
                    *reinterpret_cast<uint2*>(v);
            }
        }
        __syncthreads();
        constexpr int TPR = (BM == 128) ? 2 : 1;   // threads per output row
        int row = tid / TPR;
        int seg = (TPR == 2) ? (tid & 1) * 64 : 0;
        if (row < BN) {
            bft* dst = (bft*)Out + (size_t)bz * zO
                     + (size_t)(n0 + row) * strideO + m0 + seg;
            const unsigned short* src = &Ol[row * OST + seg];
#pragma unroll
            for (int q = 0; q < 8; ++q)
                *reinterpret_cast<uint4*>(dst + q * 8) =
                    *reinterpret_cast<const uint4*>(src + q * 8);
        }
        return;
    }
#pragma unroll
    for (int i = 0; i < FM; ++i) {
        int mB = m0 + wr * FM * 16 + i * 16 + l4 * 4;
#pragma unroll
        for (int j = 0; j < FN; ++j) {
            int n = n0 + wc * FN * 16 + j * 16 + l15;
#pragma unroll
            for (int r = 0; r < 4; ++r) {
                int m = mB + r;
                if (m >= Mreal) continue;
                float vv = acc[i][j][r];
                if constexpr (HASBIAS) vv += bias[m];
                size_t idx;
                if constexpr (OMODE == 0)
                    idx = (size_t)bz * zO + (size_t)m * strideO + n;
                else {
                    int win = n >> 6, e = n & 63;
                    int hh = ((win / 24) << 3) + (e >> 3);
                    int ww = ((win % 24) << 3) + (e & 7);
                    idx = (size_t)bz * zO + (size_t)m * S + (size_t)hh * L + ww;
                }
                if constexpr (HASRES) vv += ldf(Res + ((OMODE == 0)
                                  ? ((size_t)bz * zR + (size_t)m * strideO + n) : idx));
                stf(Out + idx, vv);
            }
        }
    }
}

// ---------------- depthwise 3x3 (batched) -> window-tiled --------------------
__global__ __launch_bounds__(BLK) void k_dwconv(const bft* __restrict__ in,
                                                long inZ,
                                                const float* __restrict__ wt,
                                                bft* __restrict__ out,
                                                long outZ) {
    int t = blockIdx.x * BLK + threadIdx.x;      // [0, Bn*Cc*S/8)
    int ch2 = t / (S / 8);
    int rem = t - ch2 * (S / 8);
    int b = ch2 / Cc, ch = ch2 - b * Cc;
    int h = rem / 24, wb = (rem - h * 24) * 8;
    const float* wp = wt + (size_t)ch * 9;
    const bft* ip = in + (size_t)b * inZ + (size_t)ch * S;
    float acc[8] = {};
#pragma unroll
    for (int dy = -1; dy <= 1; ++dy) {
        int hh = h + dy;
        if (hh < 0 || hh >= L) continue;
        const bft* rp = ip + hh * L + wb;
        float e[10];
        uint4 mid = *reinterpret_cast<const uint4*>(rp);
        const unsigned short* ms = reinterpret_cast<const unsigned short*>(&mid);
#pragma unroll
        for (int q = 0; q < 8; ++q) e[q + 1] = bu2f(ms[q]);
        e[0] = (wb > 0) ? ldf(rp - 1) : 0.f;
        e[9] = (wb + 8 < L) ? ldf(rp + 8) : 0.f;
        float c0 = wp[(dy + 1) * 3], c1 = wp[(dy + 1) * 3 + 1], c2 = wp[(dy + 1) * 3 + 2];
#pragma unroll
        for (int q = 0; q < 8; ++q)
            acc[q] += c0 * e[q] + c1 * e[q + 1] + c2 * e[q + 2];
    }
    int win = (h >> 3) * 24 + (wb >> 3);
    int e0 = (h & 7) * 8;
    unsigned short ov[8];
#pragma unroll
    for (int q = 0; q < 8; ++q) ov[q] = f2bfu(acc[q]);
    *reinterpret_cast<uint4*>(out + (size_t)b * outZ + (size_t)ch * S + win * 64 + e0) =
        *reinterpret_cast<uint4*>(ov);
}

// ---------------- window channel attention via MFMA; out = [s*][Cc] ----------
__global__ __launch_bounds__(256) void k_attn_mfma(
    const bft* __restrict__ QW, long zQ,
    const bft* __restrict__ KW, long zK,
    const bft* __restrict__ VW, long zV,
    const float* __restrict__ temp,
    bft* __restrict__ outp, long zO) {
    __shared__ unsigned short qls[4][32 * 66];
    __shared__ unsigned short kls[4][32 * 66];
    __shared__ unsigned short vls[4][32 * 66];
    __shared__ float rqs[4][32], rks[4][32];
    const int tid = threadIdx.x;
    const int wv = tid >> 6, lane = tid & 63;
    const int win = blockIdx.x * 4 + wv;
    const int hd = blockIdx.y;
    const int bz = blockIdx.z;
    const int l15 = lane & 15, l4 = lane >> 4;
    unsigned short* ql = qls[wv];
    unsigned short* kl = kls[wv];
    unsigned short* vl = vls[wv];
    const size_t base = (size_t)(hd * 32) * S + (size_t)win * 64;

#pragma unroll
    for (int i = 0; i < 4; ++i) {
        int c = i * 8 + (lane >> 3), e0 = (lane & 7) * 8;
        size_t g = base + (size_t)c * S + e0;
        uint4 vq = *reinterpret_cast<const uint4*>(QW + (size_t)bz * zQ + g);
        uint4 vk = *reinterpret_cast<const uint4*>(KW + (size_t)bz * zK + g);
        uint4 vvv = *reinterpret_cast<const uint4*>(VW + (size_t)bz * zV + g);
        unsigned int* dq = reinterpret_cast<unsigned int*>(&ql[c * 66 + e0]);
        unsigned int* dk = reinterpret_cast<unsigned int*>(&kl[c * 66 + e0]);
        unsigned int* dv = reinterpret_cast<unsigned int*>(&vl[c * 66 + e0]);
        dq[0] = vq.x; dq[1] = vq.y; dq[2] = vq.z; dq[3] = vq.w;
        dk[0] = vk.x; dk[1] = vk.y; dk[2] = vk.z; dk[3] = vk.w;
        dv[0] = vvv.x; dv[1] = vvv.y; dv[2] = vvv.z; dv[3] = vvv.w;
    }
    __syncthreads();
    {
        int row = lane & 31;
        const unsigned short* src = (lane < 32) ? ql : kl;
        float s = 0.f;
#pragma unroll
        for (int w = 0; w < 32; ++w) {
            unsigned int d = *reinterpret_cast<const unsigned int*>(&src[row * 66 + 2 * w]);
            float a = bu2f((unsigned short)(d & 0xffff));
            float b = bu2f((unsigned short)(d >> 16));
            s += a * a + b * b;
        }
        float r = 1.f / fmaxf(sqrtf(s), 1e-12f);
        if (lane < 32) rqs[wv][row] = r; else rks[wv][row] = r;
    }
    __syncthreads();
    f32x4 at[2][2] = {};
#pragma unroll
    for (int ks = 0; ks < 2; ++ks) {
        bf16x8 aq[2], bk[2];
#pragma unroll
        for (int i = 0; i < 2; ++i)
            aq[i] = ld8(&ql[(i * 16 + l15) * 66 + ks * 32 + l4 * 8]);
#pragma unroll
        for (int j = 0; j < 2; ++j)
            bk[j] = ld8(&kl[(j * 16 + l15) * 66 + ks * 32 + l4 * 8]);
#pragma unroll
        for (int i = 0; i < 2; ++i)
#pragma unroll
            for (int j = 0; j < 2; ++j)
                at[i][j] = __builtin_amdgcn_mfma_f32_16x16x32_bf16(
                    aq[i], bk[j], at[i][j], 0, 0, 0);
    }
    float tpr = temp[hd];
    float rk0 = rks[wv][l15] * tpr, rk1 = rks[wv][16 + l15] * tpr;
    float pr[2][2][4];
#pragma unroll
    for (int i = 0; i < 2; ++i)
#pragma unroll
        for (int r = 0; r < 4; ++r) {
            int c = i * 16 + l4 * 4 + r;
            float rq = rqs[wv][c];
            float v0 = at[i][0][r] * rq * rk0;
            float v1 = at[i][1][r] * rq * rk1;
            float mx = fmaxf(v0, v1);
#pragma unroll
            for (int m = 1; m < 16; m <<= 1) mx = fmaxf(mx, __shfl_xor(mx, m));
            v0 = __expf(v0 - mx);
            v1 = __expf(v1 - mx);
            float sm = v0 + v1;
#pragma unroll
            for (int m = 1; m < 16; m <<= 1) sm += __shfl_xor(sm, m);
            float inv = 1.f / sm;
            pr[i][0][r] = v0 * inv;
            pr[i][1][r] = v1 * inv;
        }
    __syncthreads();
    unsigned short* pl = ql;
#pragma unroll
    for (int i = 0; i < 2; ++i)
#pragma unroll
        for (int j = 0; j < 2; ++j)
#pragma unroll
            for (int r = 0; r < 4; ++r)
                pl[(i * 16 + l4 * 4 + r) * 34 + j * 16 + l15] = f2bfu(pr[i][j][r]);
    __syncthreads();
    bf16x8 ap[2];
#pragma unroll
    for (int i = 0; i < 2; ++i)
        ap[i] = ld8(&pl[(i * 16 + l15) * 34 + l4 * 8]);
    f32x4 o[2][4] = {};
#pragma unroll
    for (int j = 0; j < 4; ++j) {
        unsigned short tv[8];
#pragma unroll
        for (int q = 0; q < 8; ++q)
            tv[q] = vl[(l4 * 8 + q) * 66 + j * 16 + l15];
        bf16x8 bv = *reinterpret_cast<bf16x8*>(tv);
#pragma unroll
        for (int i = 0; i < 2; ++i)
            o[i][j] = __builtin_amdgcn_mfma_f32_16x16x32_bf16(ap[i], bv, o[i][j], 0, 0, 0);
    }
#pragma unroll
    for (int i = 0; i < 2; ++i)
#pragma unroll
        for (int j = 0; j < 4; ++j) {
            int e = j * 16 + l15, cl = i * 16 + l4 * 4;
            unsigned short v[4];
#pragma unroll
            for (int r = 0; r < 4; ++r) v[r] = f2bfu(o[i][j][r]);
            unsigned short* row = ((e < 32) ? kl : vl) + (e & 31) * 40 + cl;
            *reinterpret_cast<uint2*>(row) = *reinterpret_cast<uint2*>(v);
        }
    {
        const unsigned short* row = ((lane < 32) ? kl : vl) + (lane & 31) * 40;
        bft* dst = outp + (size_t)bz * zO + (size_t)(win * 64 + lane) * Cc + hd * 32;
#pragma unroll
        for (int q = 0; q < 4; ++q)
            *reinterpret_cast<uint4*>(dst + q * 8) =
                *reinterpret_cast<const uint4*>(row + q * 8);
    }
}

// ---------------- FFN gate (transposed, batched): fT -> gT -------------------
__global__ __launch_bounds__(BLK) void k_gateT(const bft* __restrict__ fTg,
                                               const float* __restrict__ wt,
                                               bft* __restrict__ gTg) {
    __shared__ float w1s[64][9];
    __shared__ float w2s[64][9];
    const int tid = threadIdx.x;
    const int cbase = blockIdx.y * 64;
    const bft* fT = fTg + (size_t)blockIdx.z * FTR * 1024;
    bft* gT = gTg + (size_t)blockIdx.z * GTR * 512;
    for (int id = tid; id < 576; id += BLK) {
        int cl = id / 9, k = id - cl * 9;
        int c = cbase + cl;
        w1s[cl][k] = (c < HID) ? wt[(size_t)c * 9 + k] : 0.f;
        w2s[cl][k] = (c < HID) ? wt[(size_t)(c + HID) * 9 + k] : 0.f;
    }
    __syncthreads();
    int px = blockIdx.x * 32 + (tid >> 3);
    int cgl = (tid & 7) * 8;
    int hc = px / L, w = px - hc * L;
    float a1[8] = {}, a2[8] = {};
#pragma unroll
    for (int dy = 0; dy < 3; ++dy) {
#pragma unroll
        for (int dx = 0; dx < 3; ++dx) {
            int ww = w + dx - 1;
            if (ww < 0 || ww >= L) continue;
            size_t frow = (size_t)((hc + dy) * L + ww) * 1024 + cbase + cgl;
            uint4 u1 = *reinterpret_cast<const uint4*>(fT + frow);
            uint4 u2 = *reinterpret_cast<const uint4*>(fT + frow + 512);
            const unsigned short* e1 = reinterpret_cast<const unsigned short*>(&u1);
            const unsigned short* e2 = reinterpret_cast<const unsigned short*>(&u2);
            int k = dy * 3 + dx;
#pragma unroll
            for (int j = 0; j < 8; ++j) {
                a1[j] += w1s[cgl + j][k] * bu2f(e1[j]);
                a2[j] += w2s[cgl + j][k] * bu2f(e2[j]);
            }
        }
    }
    unsigned short ov[8];
#pragma unroll
    for (int j = 0; j < 8; ++j) {
        float ge = 0.5f * a1[j] * (1.f + erff(a1[j] * 0.70710678118654752f));
        ov[j] = f2bfu(ge * a2[j]);
    }
    *reinterpret_cast<uint4*>(gT + (size_t)px * 512 + cbase + cgl) =
        *reinterpret_cast<uint4*>(ov);
}

// -----------------------------------------------------------------------------
extern "C" void kernel_launch(void* const* d_in, const int* in_sizes, int n_in,
                              void* d_out, int out_size, void* d_ws, size_t ws_size,
                              hipStream_t stream) {
    const float* x      = (const float*)d_in[0];
    const float* n1w    = (const float*)d_in[1];
    const float* n1b    = (const float*)d_in[2];
    const float* w_qkv  = (const float*)d_in[3];
    const float* w_dw   = (const float*)d_in[4];
    const float* temp   = (const float*)d_in[5];
    const float* w_proj = (const float*)d_in[6];
    const float* b_proj = (const float*)d_in[7];
    const float* n2w    = (const float*)d_in[8];
    const float* n2b    = (const float*)d_in[9];
    const float* w_in   = (const float*)d_in[10];
    const float* w_dwf  = (const float*)d_in[11];
    const float* w_out  = (const float*)d_in[12];
    float* outp = (float*)d_out;

    // workspace: 170,901,504 bytes (2-batch buffers)
    const long CS = (long)Cc * S;
    const size_t DCT_B = 147456;
    const size_t BUF_B = (size_t)Bn * CS * 2;
    const size_t QKV_B = (size_t)Bn * 3 * CS * 2;
    const size_t WB_B  = 884736;
    const size_t NEED  = DCT_B + 3 * BUF_B + QKV_B + WB_B;
    if (ws_size < NEED) return;

    char* p = (char*)d_ws;
    bft* dctb  = (bft*)p;
    bft* dctTb = dctb + L * L;
    p += DCT_B;
    bft* X1    = (bft*)p;                  p += BUF_B;
    bft* PbB   = (bft*)p;                  p += BUF_B;
    bft* QbB   = (bft*)p;                  p += BUF_B;
    bft* QKV   = (bft*)p;                  p += QKV_B;
    bft* w_qkv_b = (bft*)p;
    bft* w_proj_b = w_qkv_b + 576 * 192;
    bft* w_in_b  = w_proj_b + 192 * 192;
    bft* w_out_b = w_in_b + 1024 * 192;
    bft* fT = QKV;
    bft* gT = QKV + (size_t)Bn * FTR * 1024;
    bft* attnT = QKV + CS;

    k_dct_init<<<144, BLK, 0, stream>>>(dctb, dctTb);
    k_cvt<<<432, BLK, 0, stream>>>(w_qkv, w_qkv_b, 576, 192, 192);
    k_cvt<<<144, BLK, 0, stream>>>(w_proj, w_proj_b, 192, 192, 192);
    k_cvt_ffn<<<768, BLK, 0, stream>>>(w_in, w_in_b);
    k_cvt<<<384, BLK, 0, stream>>>(w_out, w_out_b, 192, 510, 512);

    // ---------------- attention branch (both batches per dispatch) -----------
    k_ln8<float><<<dim3(S * 8 / BLK, Bn), BLK, 0, stream>>>(x, n1w, n1b, PbB, CS, CS);
    k_mm<2, 2, 2, 6, 64, 2, 3, false, false, bft, float><<<dim3(1, 3, Bn * Cc), 256, 0, stream>>>(
        PbB, L, L, S,  dctb, L, 0,  QbB, L, S,  nullptr, nullptr, 0,  L, 0, 0);
    k_mm<2, 2, 2, 6, 64, 2, 3, false, false, bft, float><<<dim3(1, 3, Bn * Cc), 256, 0, stream>>>(
        QbB, L, L, S,  dctb, L, 0,  PbB, L, S,  nullptr, nullptr, 0,  L, 0, 0);
    k_tr<<<dim3(576, 6, Bn), BLK, 0, stream>>>(PbB, QbB, CS);
    k_mm<2, 2, 4, 4, 64, 2, 0, false, false, bft, float><<<dim3(288, 5, Bn), 256, 0, stream>>>(
        w_qkv_b, Cc, 576, 0,  QbB, Cc, CS,  QKV, S, 3 * CS,  nullptr, nullptr, 0,  Cc, 0, 0);
    k_dwconv<<<6912, BLK, 0, stream>>>(QKV, 3 * CS, w_dw, PbB, CS);
    k_dwconv<<<6912, BLK, 0, stream>>>(QKV + CS, 3 * CS, w_dw + Cc * 9, QbB, CS);
    k_dwconv<<<6912, BLK, 0, stream>>>(QKV + 2 * CS, 3 * CS, w_dw + 2 * Cc * 9, QKV, 3 * CS);
    k_attn_mfma<<<dim3(144, 6, Bn), 256, 0, stream>>>(
        PbB, CS, QbB, CS, QKV, 3 * CS, temp, attnT, 3 * CS);
    k_mm<2, 2, 4, 4, 64, 2, 2, true, false, bft, float><<<dim3(288, 2, Bn), 256, 0, stream>>>(
        w_proj_b, Cc, Cc, 0,  attnT, Cc, 3 * CS,  QbB, S, CS,  b_proj, nullptr, 0,  Cc, 0, 0);
    k_mm<2, 2, 2, 6, 64, 2, 3, false, false, bft, float><<<dim3(1, 3, Bn * Cc), 256, 0, stream>>>(
        QbB, L, L, S,  dctTb, L, 0,  PbB, L, S,  nullptr, nullptr, 0,  L, 0, 0);
    k_mm<2, 2, 2, 6, 64, 2, 0, false, true, bft, float><<<dim3(1, 3, Bn * Cc), 256, 0, stream>>>(
        dctTb, L, L, 0,  PbB, L, S,  X1, L, S,  nullptr, x, S,  L, 0, 0);

    // ---------------- FFN branch (both batches per dispatch) -----------------
    k_lnT8<bft><<<dim3(S * 8 / BLK, Bn), BLK, 0, stream>>>(X1, n2w, n2b, QbB, CS, CS);
    for (int ck = 0; ck < 3; ++ck) {
        int h0 = ck * CH;
        long off = (long)(h0 - 1) * L;
        int rlo = (h0 == 0) ? L : 0;
        int rhi = (h0 == 2 * CH) ? (FTR - L) : FTR;
        k_mm<2, 2, 4, 4, 64, 4, 3, false, false, bft, float><<<dim3(99, 8, Bn), 256, 0, stream>>>(
            w_in_b, Cc, 1024, 0,  QbB + off * Cc, Cc, CS,  fT, 1024, (long)FTR * 1024,
            nullptr, nullptr, 0,  Cc, rlo, rhi);
        k_gateT<<<dim3(GTR / 32, 8, Bn), BLK, 0, stream>>>(fT, w_dwf, gT);
        k_mm<2, 2, 2, 4, 64, 2, 0, false, true, float, bft><<<dim3(96, 3, Bn), 256, 0, stream>>>(
            w_out_b, 512, 192, 0,  gT, 512, (long)GTR * 512,
            outp + (size_t)h0 * L, S, CS,
            nullptr, X1 + (size_t)h0 * L, CS,  512, 0, 0);
    }
}